// Round 4
// baseline (472.765 us; speedup 1.0000x reference)
//
#include <hip/hip_runtime.h>
#include <hip/hip_bf16.h>

// Problem constants: N=50000, E=1600000, D=3, IN=32, OUT=32, KS=4, K=64, S=8
// Atomic-free structure (resubmission of round-3 source; round-3 bench was an
// infra failure — container acquisition failed twice, no test output):
//   prep: pack W/f to bf16, bucket-hist (27), row-hist (deg, 50K)
//   scan27 / scan_rows: prefix sums
//   bucket_scatter: counting-sort edges by spline base; also scatter each
//                   edge's sorted position into a row-CSR position list
//   edge_mfma_nw: per-bucket MFMA, per-edge 32-ch message -> bf16 packed,
//                 coalesced non-atomic stores at bucket-sorted positions
//   gather_out: per node, sum its messages via the row-CSR (single writer,
//               no atomics), divide by deg, add bias
#define NN 50000
#define EE 1600000
#define BPB 64       // blocks per bucket in edge_mfma_nw

typedef __attribute__((ext_vector_type(8))) short  s16x8;   // 8 bf16 (4 VGPRs)
typedef __attribute__((ext_vector_type(4))) float  f32x4;   // MFMA C/D frag

static __device__ __forceinline__ short f2bs(float x) {
  __hip_bfloat16 h = __float2bfloat16(x);
  short s; __builtin_memcpy(&s, &h, 2); return s;
}

__constant__ int kOffs[8] = {0, 1, 4, 5, 16, 17, 20, 21};

// ---------------------------------------------------------------------------
// prep (fused): blocks [0,32) conv_w ; [32,160) pack_f ; [160,416) hists.
// conv_w: W fp32 [k][i][o] -> bf16 B-frag layout. Tile t = kmat*2+oh covers
// cols [t*16,t*16+16); frag elem (t,l,j) = B[k=(l>>4)*8+j][c=t*16+(l&15)],
// B[k][c] = W[c>>5][k][c&31].
// pack_f: f fp32 [N][32] -> bf16 [N][32] (3.2 MB; IS the MFMA A-fragment).
// hists: bucket q = b0+3*b1+9*b2 (27 bins, LDS-staged) + row degree (int).
// ---------------------------------------------------------------------------
#define PREP_BLOCKS 416
__global__ __launch_bounds__(256) void prep(const float* __restrict__ W,
                                            const float* __restrict__ f,
                                            const float* __restrict__ pseudo,
                                            const int* __restrict__ ei,
                                            short* __restrict__ Wb,
                                            short* __restrict__ fbh,
                                            int* __restrict__ hist,
                                            int* __restrict__ degi) {
  const int b = blockIdx.x;
  if (b < 32) {
    int tid = b * 256 + threadIdx.x;               // 8192 threads, one frag each
    int t = tid >> 6, l = tid & 63;
    int c = t * 16 + (l & 15);
    int k0 = (l >> 4) * 8;
    s16x8 frag;
#pragma unroll
    for (int j = 0; j < 8; ++j)
      frag[j] = f2bs(W[(c >> 5) * 1024 + (k0 + j) * 32 + (c & 31)]);
    ((s16x8*)Wb)[tid] = frag;
  } else if (b < 160) {
    for (int tid = (b - 32) * 256 + threadIdx.x; tid < NN * 32 / 8; tid += 128 * 256) {
      const f32x4* fp = (const f32x4*)f + (size_t)tid * 2;
      f32x4 a = fp[0], c = fp[1];
      s16x8 o;
#pragma unroll
      for (int j = 0; j < 4; ++j) { o[j] = f2bs(a[j]); o[4 + j] = f2bs(c[j]); }
      ((s16x8*)fbh)[tid] = o;
    }
  } else {
    __shared__ int lh[27];
    if (threadIdx.x < 27) lh[threadIdx.x] = 0;
    __syncthreads();
    for (int e = (b - 160) * 256 + threadIdx.x; e < EE; e += 256 * 256) {
      float v0 = pseudo[e * 3 + 0] * 3.0f;
      float v1 = pseudo[e * 3 + 1] * 3.0f;
      float v2 = pseudo[e * 3 + 2] * 3.0f;
      int b0 = (int)fminf(fmaxf(floorf(v0), 0.0f), 2.0f);
      int b1 = (int)fminf(fmaxf(floorf(v1), 0.0f), 2.0f);
      int b2 = (int)fminf(fmaxf(floorf(v2), 0.0f), 2.0f);
      atomicAdd(&lh[b0 + 3 * b1 + 9 * b2], 1);
      atomicAdd(&degi[ei[e]], 1);                  // row degree histogram
    }
    __syncthreads();
    if (threadIdx.x < 27) atomicAdd(hist + threadIdx.x, lh[threadIdx.x]);
  }
}

// ---------------------------------------------------------------------------
// Exclusive scan of 27 bucket counts (one wave, shfl prefix).
// ---------------------------------------------------------------------------
__global__ void scan27(const int* __restrict__ hist,
                       int* __restrict__ bstart,
                       int* __restrict__ cursor) {
  int l = threadIdx.x;                             // 64 threads
  int v = (l < 27) ? hist[l] : 0;
  int x = v;
#pragma unroll
  for (int d = 1; d < 32; d <<= 1) {
    int y = __shfl_up(x, d, 64);
    if (l >= d) x += y;
  }
  if (l < 27) { bstart[l] = x - v; cursor[l] = x - v; }
  if (l == 26) bstart[27] = x;                     // total = EE
}

// ---------------------------------------------------------------------------
// Exclusive scan of degi[50000] -> rstart[0..NN], plus cursor copy rcur.
// Single block of 1024 threads, 49 chunks, carry in LDS.
// ---------------------------------------------------------------------------
__global__ __launch_bounds__(1024) void scan_rows(const int* __restrict__ degi,
                                                  int* __restrict__ rstart,
                                                  int* __restrict__ rcur) {
  __shared__ int carry;
  __shared__ int tot;
  __shared__ int wsum[16];
  if (threadIdx.x == 0) carry = 0;
  __syncthreads();
  const int lane = threadIdx.x & 63;
  const int wid  = threadIdx.x >> 6;
  for (int c0 = 0; c0 < NN; c0 += 1024) {
    int i = c0 + threadIdx.x;
    int v = (i < NN) ? degi[i] : 0;
    int x = v;
#pragma unroll
    for (int d = 1; d < 64; d <<= 1) {
      int y = __shfl_up(x, d, 64);
      if (lane >= d) x += y;
    }
    if (lane == 63) wsum[wid] = x;
    __syncthreads();                               // wsum ready
    if (threadIdx.x == 0) {
      int run = 0;
#pragma unroll
      for (int w = 0; w < 16; ++w) { int t = wsum[w]; wsum[w] = run; run += t; }
      tot = run;
    }
    __syncthreads();                               // wsum exclusive, tot ready
    int excl = carry + wsum[wid] + (x - v);
    if (i < NN) { rstart[i] = excl; rcur[i] = excl; }
    __syncthreads();                               // all reads of carry done
    if (threadIdx.x == 0) carry += tot;
    __syncthreads();
  }
  if (threadIdx.x == 0) rstart[NN] = carry;        // == EE
}

// ---------------------------------------------------------------------------
// Counting-sort scatter. Per-block LDS ranks + one cursor atomic per bucket
// per block -> contiguous runs. edata[pos] = (p0,p1,p2, bitcast(col)).
// Also writes the row-CSR position list: posl[rcur[row]++] = pos.
// ---------------------------------------------------------------------------
#define SCPER 8
__global__ __launch_bounds__(256) void bucket_scatter(const float* __restrict__ pseudo,
                                                      const int* __restrict__ ei,
                                                      int* __restrict__ cursor,
                                                      int* __restrict__ rcur,
                                                      float4* __restrict__ edata,
                                                      int* __restrict__ posl) {
  __shared__ int lh[27];
  __shared__ int bb[27];
  if (threadIdx.x < 27) lh[threadIdx.x] = 0;
  __syncthreads();
  const int e0 = blockIdx.x * 256 * SCPER;
  float p0[SCPER], p1[SCPER], p2[SCPER];
  int rk[SCPER], bq[SCPER];
#pragma unroll
  for (int i = 0; i < SCPER; ++i) {
    int e = e0 + i * 256 + threadIdx.x;
    bq[i] = -1;
    if (e < EE) {
      float a0 = pseudo[e * 3 + 0];
      float a1 = pseudo[e * 3 + 1];
      float a2 = pseudo[e * 3 + 2];
      int b0 = (int)fminf(fmaxf(floorf(a0 * 3.0f), 0.0f), 2.0f);
      int b1 = (int)fminf(fmaxf(floorf(a1 * 3.0f), 0.0f), 2.0f);
      int b2 = (int)fminf(fmaxf(floorf(a2 * 3.0f), 0.0f), 2.0f);
      int q = b0 + 3 * b1 + 9 * b2;
      p0[i] = a0; p1[i] = a1; p2[i] = a2;
      rk[i] = atomicAdd(&lh[q], 1);
      bq[i] = q;
    }
  }
  __syncthreads();
  if (threadIdx.x < 27) bb[threadIdx.x] = atomicAdd(&cursor[threadIdx.x], lh[threadIdx.x]);
  __syncthreads();
#pragma unroll
  for (int i = 0; i < SCPER; ++i) {
    if (bq[i] < 0) continue;
    int e = e0 + i * 256 + threadIdx.x;
    int pos = bb[bq[i]] + rk[i];
    int row = ei[e], col = ei[EE + e];
    edata[pos] = make_float4(p0[i], p1[i], p2[i], __int_as_float(col));
    int pp = atomicAdd(&rcur[row], 1);
    posl[pp] = pos;
  }
}

// ---------------------------------------------------------------------------
// Bucketed MFMA, atomic-free. Per group of 16 edges:
//   A-row m: bf16 f[col_m] (unscaled); per s: d = mfma(A, W[base+off_s], 0);
//   msg row += w_s(edge) * d  (fp32, weights via __shfl from lane edge).
// Store: channel-permuted packed bf16: msg_u32[pos*16 + och] =
//   pk(bf16(acc0), bf16(acc1))  -> c' = 2*och (o=och), 2*och+1 (o=och+16).
// 4 coalesced u32 stores/lane/group (256 B per store instruction).
// Next-group edata + A-frag are prefetched to hide gather latency.
// D layout (m89-verified): col=lane&15, row=(lane>>4)*4+reg.
// ---------------------------------------------------------------------------
__global__ __launch_bounds__(256) void edge_mfma_nw(const float4* __restrict__ edata,
                                                    const short* __restrict__ fbh,
                                                    const short* __restrict__ Wb,
                                                    const int* __restrict__ bstart,
                                                    unsigned* __restrict__ msg) {
  const int q   = blockIdx.x / BPB;
  const int sub = blockIdx.x % BPB;
  const int l   = threadIdx.x & 63;
  const int wid = threadIdx.x >> 6;

  const int start = bstart[q];
  const int end   = bstart[q + 1];
  const int nE    = end - start;
  if (nE <= 0) return;
  const int ngroups = (nE + 15) >> 4;

  const int b0 = q % 3, b1 = (q / 3) % 3, b2 = q / 9;
  const int base = b0 + 4 * b1 + 16 * b2;
  const int ko[8] = {0, 1, 4, 5, 16, 17, 20, 21};

  s16x8 bf[8][2];                                  // bucket's B frags, 64 VGPRs
#pragma unroll
  for (int s = 0; s < 8; ++s) {
    int kmat = base + ko[s];
#pragma unroll
    for (int oh = 0; oh < 2; ++oh)
      bf[s][oh] = ((const s16x8*)Wb)[(kmat * 2 + oh) * 64 + l];
  }

  const int m   = l & 15;         // A-row edge-in-group for this lane
  const int och = l & 15;         // D column within tile
  const int eb  = (l >> 4) * 4;   // first D-row edge in this lane's quarter
  const int kq  = l >> 4;
  const int stride = BPB * 4;

  int g = sub * 4 + wid;
  if (g >= ngroups) return;

  int idx = start + g * 16 + m;
  float4 ed = edata[idx < end ? idx : start];
  s16x8  af = ((const s16x8*)fbh)[(size_t)__float_as_int(ed.w) * 4 + kq];

  while (true) {
    const int gn = g + stride;
    const bool more = gn < ngroups;
    int idxn = start + gn * 16 + m;
    float4 edn = edata[(more && idxn < end) ? idxn : start];  // prefetch

    // spline weights of this lane's A-edge (garbage for tail lanes is fine:
    // tail rows' stores are guarded below, MFMA rows are independent)
    float f0 = ed.x * 3.0f - (float)b0;
    float f1 = ed.y * 3.0f - (float)b1;
    float f2 = ed.z * 3.0f - (float)b2;
    float g0 = 1.0f - f0, g1c = 1.0f - f1, g2c = 1.0f - f2;
    float w8[8];
    w8[0] = g0 * g1c * g2c; w8[1] = f0 * g1c * g2c;
    w8[2] = g0 * f1 * g2c;  w8[3] = f0 * f1 * g2c;
    w8[4] = g0 * g1c * f2;  w8[5] = f0 * g1c * f2;
    w8[6] = g0 * f1 * f2;   w8[7] = f0 * f1 * f2;

    // prefetch next A-frag (hides fbh gather under MFMA+store)
    s16x8 afn = ((const s16x8*)fbh)[(size_t)__float_as_int(edn.w) * 4 + kq];

    f32x4 acc0 = {0.f, 0.f, 0.f, 0.f}, acc1 = {0.f, 0.f, 0.f, 0.f};
#pragma unroll
    for (int s = 0; s < 8; ++s) {
      f32x4 d0 = __builtin_amdgcn_mfma_f32_16x16x32_bf16(af, bf[s][0],
                   (f32x4){0.f, 0.f, 0.f, 0.f}, 0, 0, 0);
      f32x4 d1 = __builtin_amdgcn_mfma_f32_16x16x32_bf16(af, bf[s][1],
                   (f32x4){0.f, 0.f, 0.f, 0.f}, 0, 0, 0);
#pragma unroll
      for (int r = 0; r < 4; ++r) {
        float wsr = __shfl(w8[s], eb + r, 64);
        acc0[r] += wsr * d0[r];
        acc1[r] += wsr * d1[r];
      }
    }

#pragma unroll
    for (int r = 0; r < 4; ++r) {
      int ridx = g * 16 + eb + r;                  // bucket-local row
      if (ridx < nE) {
        unsigned lo = (unsigned)(unsigned short)f2bs(acc0[r]);
        unsigned hi = (unsigned)(unsigned short)f2bs(acc1[r]);
        msg[(size_t)(start + ridx) * 16 + och] = lo | (hi << 16);
      }
    }

    if (!more) break;
    g = gn; ed = edn; af = afn;
  }
}

// ---------------------------------------------------------------------------
// Per-node gather: 16 lanes/node. Sum bf16 messages in fp32 via row-CSR,
// divide by deg (= rstart diff), add bias. Single writer -> no atomics.
// Lane j holds channels o=j (lo halves) and o=j+16 (hi halves).
// ---------------------------------------------------------------------------
__global__ __launch_bounds__(256) void gather_out(const unsigned* __restrict__ msg,
                                                  const int* __restrict__ posl,
                                                  const int* __restrict__ rstart,
                                                  const float* __restrict__ bias,
                                                  float* __restrict__ out) {
  int n = (blockIdx.x * 256 + threadIdx.x) >> 4;   // node
  int j = threadIdx.x & 15;
  if (n >= NN) return;
  int s = rstart[n], e = rstart[n + 1];
  float s0 = 0.f, s1 = 0.f;
  int i = s;
  for (; i + 2 <= e; i += 2) {                     // unroll-2 for latency ILP
    int pA = posl[i], pB = posl[i + 1];
    unsigned uA = msg[(size_t)pA * 16 + j];
    unsigned uB = msg[(size_t)pB * 16 + j];
    s0 += __uint_as_float(uA << 16);
    s1 += __uint_as_float(uA & 0xFFFF0000u);
    s0 += __uint_as_float(uB << 16);
    s1 += __uint_as_float(uB & 0xFFFF0000u);
  }
  if (i < e) {
    unsigned u = msg[(size_t)posl[i] * 16 + j];
    s0 += __uint_as_float(u << 16);
    s1 += __uint_as_float(u & 0xFFFF0000u);
  }
  float d = fmaxf((float)(e - s), 1.0f);
  out[n * 32 + j]      = s0 / d + bias[j];
  out[n * 32 + 16 + j] = s1 / d + bias[16 + j];
}

// ---------------------------------------------------------------------------
// Fallback path (small workspace): direct per-edge compute + atomics.
// ---------------------------------------------------------------------------
static __device__ __forceinline__ void spline_basis(const float* __restrict__ pseudo,
                                                    int e, float w[8], int& base) {
  float v0 = pseudo[e * 3 + 0] * 3.0f;
  float v1 = pseudo[e * 3 + 1] * 3.0f;
  float v2 = pseudo[e * 3 + 2] * 3.0f;
  float b0 = fmaxf(fminf(floorf(v0), 2.0f), 0.0f);
  float b1 = fmaxf(fminf(floorf(v1), 2.0f), 0.0f);
  float b2 = fmaxf(fminf(floorf(v2), 2.0f), 0.0f);
  float f0 = v0 - b0, f1 = v1 - b1, f2 = v2 - b2;
  float g0 = 1.0f - f0, g1 = 1.0f - f1, g2 = 1.0f - f2;
  base = (int)b0 + 4 * (int)b1 + 16 * (int)b2;
  w[0] = g0 * g1 * g2; w[1] = f0 * g1 * g2;
  w[2] = g0 * f1 * g2; w[3] = f0 * f1 * g2;
  w[4] = g0 * g1 * f2; w[5] = f0 * g1 * f2;
  w[6] = g0 * f1 * f2; w[7] = f0 * f1 * f2;
}

__global__ __launch_bounds__(256) void edge_direct(const float* __restrict__ pseudo,
                                                   const int* __restrict__ ei,
                                                   const float* __restrict__ f,
                                                   const float* __restrict__ W,
                                                   float* __restrict__ acc,
                                                   float* __restrict__ deg) {
  const int tid = blockIdx.x * 256 + threadIdx.x;
  const int e = tid >> 5;
  const int o = tid & 31;
  if (e >= EE) return;
  const int row = ei[e];
  const int col = ei[EE + e];
  float w[8]; int base;
  spline_basis(pseudo, e, w, base);
  const float myf = f[col * 32 + o];
  float a = 0.0f;
  for (int i = 0; i < 32; ++i) {
    float fi = __shfl(myf, i, 32);
    float wsum = 0.0f;
#pragma unroll
    for (int s = 0; s < 8; ++s)
      wsum += w[s] * W[(size_t)(base + kOffs[s]) * 1024 + i * 32 + o];
    a += fi * wsum;
  }
  atomicAdd(acc + (size_t)row * 32 + o, a);
  if (o == 0) atomicAdd(deg + row, 1.0f);
}

__global__ __launch_bounds__(256) void finalize(const float* __restrict__ acc,
                                                const float* __restrict__ deg,
                                                const float* __restrict__ bias,
                                                float* __restrict__ out) {
  int tid = blockIdx.x * 256 + threadIdx.x;
  if (tid >= NN * 32) return;
  int n = tid >> 5, o = tid & 31;
  float d = fmaxf(deg[n], 1.0f);
  out[tid] = acc[tid] / d + bias[o];
}

extern "C" void kernel_launch(void* const* d_in, const int* in_sizes, int n_in,
                              void* d_out, int out_size, void* d_ws, size_t ws_size,
                              hipStream_t stream) {
  const float* f      = (const float*)d_in[0];
  const float* pseudo = (const float*)d_in[1];
  const float* W      = (const float*)d_in[2];
  const float* bias   = (const float*)d_in[3];
  const int*   ei     = (const int*)d_in[4];
  float* out = (float*)d_out;

  // Workspace layout (~138.4 MB total; round 0 proved ws >= 211 MB exists)
  constexpr size_t HIST_OFF = 0;                       // 27 ints
  constexpr size_t DEGI_OFF = 128;                     // NN ints
  constexpr size_t ZERO_SZ  = 128 + (size_t)NN * 4;    // memset: hist + degi
  constexpr size_t BST_OFF  = 200192;                  // 28 ints
  constexpr size_t CUR_OFF  = BST_OFF + 128;           // 27 ints
  constexpr size_t RST_OFF  = CUR_OFF + 128;           // NN+1 ints
  constexpr size_t RCUR_OFF = RST_OFF + 200064;        // NN ints
  constexpr size_t ED_OFF   = RCUR_OFF + 200064;       // 16B aligned
  constexpr size_t ED_SZ    = (size_t)EE * 16;         // 25,600,000
  constexpr size_t POSL_OFF = ED_OFF + ED_SZ;
  constexpr size_t POSL_SZ  = (size_t)EE * 4;          //  6,400,000
  constexpr size_t MSG_OFF  = POSL_OFF + POSL_SZ;
  constexpr size_t MSG_SZ   = (size_t)EE * 64;         // 102,400,000
  constexpr size_t FBH_OFF  = MSG_OFF + MSG_SZ;
  constexpr size_t FBH_SZ   = (size_t)NN * 32 * 2;     //  3,200,000
  constexpr size_t WB_OFF   = FBH_OFF + FBH_SZ;
  constexpr size_t WB_SZ    = 128 * 64 * 8 * 2;        //    131,072
  constexpr size_t TOTAL    = WB_OFF + WB_SZ;

  char* ws = (char*)d_ws;

  if (ws_size >= TOTAL) {
    int*      hist  = (int*)(ws + HIST_OFF);
    int*      degi  = (int*)(ws + DEGI_OFF);
    int*      bst   = (int*)(ws + BST_OFF);
    int*      cur   = (int*)(ws + CUR_OFF);
    int*      rst   = (int*)(ws + RST_OFF);
    int*      rcur  = (int*)(ws + RCUR_OFF);
    float4*   edata = (float4*)(ws + ED_OFF);
    int*      posl  = (int*)(ws + POSL_OFF);
    unsigned* msg   = (unsigned*)(ws + MSG_OFF);
    short*    fbh   = (short*)(ws + FBH_OFF);
    short*    Wb    = (short*)(ws + WB_OFF);

    hipMemsetAsync(ws, 0, ZERO_SZ, stream);
    prep<<<PREP_BLOCKS, 256, 0, stream>>>(W, f, pseudo, ei, Wb, fbh, hist, degi);
    scan27<<<1, 64, 0, stream>>>(hist, bst, cur);
    scan_rows<<<1, 1024, 0, stream>>>(degi, rst, rcur);
    bucket_scatter<<<(EE + 256 * SCPER - 1) / (256 * SCPER), 256, 0, stream>>>(
        pseudo, ei, cur, rcur, edata, posl);
    edge_mfma_nw<<<27 * BPB, 256, 0, stream>>>(edata, fbh, Wb, bst, msg);
    gather_out<<<(NN * 16 + 255) / 256, 256, 0, stream>>>(msg, posl, rst, bias, out);
  } else {
    constexpr size_t ACC_SZ = (size_t)NN * 32 * 4;
    float* acc = (float*)ws;
    float* deg = (float*)(ws + ACC_SZ);
    hipMemsetAsync(acc, 0, ACC_SZ + (size_t)NN * 4, stream);
    edge_direct<<<(EE * 32) / 256, 256, 0, stream>>>(pseudo, ei, f, W, acc, deg);
    finalize<<<(NN * 32) / 256, 256, 0, stream>>>(acc, deg, bias, out);
  }
}

// Round 5
// 336.989 us; speedup vs baseline: 1.4029x; 1.4029x over previous
//
#include <hip/hip_runtime.h>
#include <hip/hip_bf16.h>

// Problem constants: N=50000, E=1600000, D=3, IN=32, OUT=32, KS=4, K=64, S=8
// Atomic-light, indirection-free structure:
//   prep: pack W/f to bf16, bucket-hist (27), row-degree hist whose atomic
//         RETURN VALUE is saved as rrank[e] (within-row rank, free).
//   scan27 / scan_rows: prefix sums (bucket starts, row-CSR starts).
//   bucket_scatter: counting-sort edges by spline base; rpos_arr[bucketpos] =
//         rstart[row] + rrank[e]  (NO atomics, NO scattered 4B writes).
//   edge_mfma_nw: per-bucket MFMA; stores each edge's 32-ch bf16 message
//         directly at its ROW-SORTED slot (64 B = exactly one cache line,
//         scattered but full-line -> no write amplification).
//   gather_out: per node, messages are CONTIGUOUS [rstart[n],rstart[n+1]) ->
//         fully coalesced streaming sum, /deg, +bias. No atomics anywhere
//         downstream of prep.
#define NN 50000
#define EE 1600000
#define BPB 64       // blocks per bucket in edge_mfma_nw

typedef __attribute__((ext_vector_type(8))) short  s16x8;   // 8 bf16 (4 VGPRs)
typedef __attribute__((ext_vector_type(4))) float  f32x4;   // MFMA C/D frag

static __device__ __forceinline__ short f2bs(float x) {
  __hip_bfloat16 h = __float2bfloat16(x);
  short s; __builtin_memcpy(&s, &h, 2); return s;
}

__constant__ int kOffs[8] = {0, 1, 4, 5, 16, 17, 20, 21};

// ---------------------------------------------------------------------------
// prep (fused): blocks [0,32) conv_w ; [32,160) pack_f ; [160,416) hists.
// conv_w: W fp32 [k][i][o] -> bf16 B-frag layout (tile t=kmat*2+oh; frag elem
// (t,l,j) = B[k=(l>>4)*8+j][c=t*16+(l&15)], B[k][c]=W[c>>5][k][c&31]).
// pack_f: f fp32 [N][32] -> bf16 [N][32] (3.2 MB; IS the MFMA A-fragment).
// hists: bucket q = b0+3*b1+9*b2 (27 bins, LDS-staged) + row degree atomic
//        whose return value is the edge's within-row rank -> rrank[e].
// ---------------------------------------------------------------------------
#define PREP_BLOCKS 416
__global__ __launch_bounds__(256) void prep(const float* __restrict__ W,
                                            const float* __restrict__ f,
                                            const float* __restrict__ pseudo,
                                            const int* __restrict__ ei,
                                            short* __restrict__ Wb,
                                            short* __restrict__ fbh,
                                            int* __restrict__ hist,
                                            int* __restrict__ degi,
                                            int* __restrict__ rrank) {
  const int b = blockIdx.x;
  if (b < 32) {
    int tid = b * 256 + threadIdx.x;               // 8192 threads, one frag each
    int t = tid >> 6, l = tid & 63;
    int c = t * 16 + (l & 15);
    int k0 = (l >> 4) * 8;
    s16x8 frag;
#pragma unroll
    for (int j = 0; j < 8; ++j)
      frag[j] = f2bs(W[(c >> 5) * 1024 + (k0 + j) * 32 + (c & 31)]);
    ((s16x8*)Wb)[tid] = frag;
  } else if (b < 160) {
    for (int tid = (b - 32) * 256 + threadIdx.x; tid < NN * 32 / 8; tid += 128 * 256) {
      const f32x4* fp = (const f32x4*)f + (size_t)tid * 2;
      f32x4 a = fp[0], c = fp[1];
      s16x8 o;
#pragma unroll
      for (int j = 0; j < 4; ++j) { o[j] = f2bs(a[j]); o[4 + j] = f2bs(c[j]); }
      ((s16x8*)fbh)[tid] = o;
    }
  } else {
    __shared__ int lh[27];
    if (threadIdx.x < 27) lh[threadIdx.x] = 0;
    __syncthreads();
    for (int e = (b - 160) * 256 + threadIdx.x; e < EE; e += 256 * 256) {
      float v0 = pseudo[e * 3 + 0] * 3.0f;
      float v1 = pseudo[e * 3 + 1] * 3.0f;
      float v2 = pseudo[e * 3 + 2] * 3.0f;
      int b0 = (int)fminf(fmaxf(floorf(v0), 0.0f), 2.0f);
      int b1 = (int)fminf(fmaxf(floorf(v1), 0.0f), 2.0f);
      int b2 = (int)fminf(fmaxf(floorf(v2), 0.0f), 2.0f);
      atomicAdd(&lh[b0 + 3 * b1 + 9 * b2], 1);
      rrank[e] = atomicAdd(&degi[ei[e]], 1);       // rank = free atomic return
    }
    __syncthreads();
    if (threadIdx.x < 27) atomicAdd(hist + threadIdx.x, lh[threadIdx.x]);
  }
}

// ---------------------------------------------------------------------------
// Exclusive scan of 27 bucket counts (one wave, shfl prefix).
// ---------------------------------------------------------------------------
__global__ void scan27(const int* __restrict__ hist,
                       int* __restrict__ bstart,
                       int* __restrict__ cursor) {
  int l = threadIdx.x;                             // 64 threads
  int v = (l < 27) ? hist[l] : 0;
  int x = v;
#pragma unroll
  for (int d = 1; d < 32; d <<= 1) {
    int y = __shfl_up(x, d, 64);
    if (l >= d) x += y;
  }
  if (l < 27) { bstart[l] = x - v; cursor[l] = x - v; }
  if (l == 26) bstart[27] = x;                     // total = EE
}

// ---------------------------------------------------------------------------
// Exclusive scan of degi[50000] -> rstart[0..NN].
// Single block of 1024 threads, 49 chunks, carry in LDS.
// ---------------------------------------------------------------------------
__global__ __launch_bounds__(1024) void scan_rows(const int* __restrict__ degi,
                                                  int* __restrict__ rstart) {
  __shared__ int carry;
  __shared__ int tot;
  __shared__ int wsum[16];
  if (threadIdx.x == 0) carry = 0;
  __syncthreads();
  const int lane = threadIdx.x & 63;
  const int wid  = threadIdx.x >> 6;
  for (int c0 = 0; c0 < NN; c0 += 1024) {
    int i = c0 + threadIdx.x;
    int v = (i < NN) ? degi[i] : 0;
    int x = v;
#pragma unroll
    for (int d = 1; d < 64; d <<= 1) {
      int y = __shfl_up(x, d, 64);
      if (lane >= d) x += y;
    }
    if (lane == 63) wsum[wid] = x;
    __syncthreads();                               // wsum ready
    if (threadIdx.x == 0) {
      int run = 0;
#pragma unroll
      for (int w = 0; w < 16; ++w) { int t = wsum[w]; wsum[w] = run; run += t; }
      tot = run;
    }
    __syncthreads();                               // wsum exclusive, tot ready
    int excl = carry + wsum[wid] + (x - v);
    if (i < NN) rstart[i] = excl;
    __syncthreads();                               // all reads of carry done
    if (threadIdx.x == 0) carry += tot;
    __syncthreads();
  }
  if (threadIdx.x == 0) rstart[NN] = carry;        // == EE
}

// ---------------------------------------------------------------------------
// Counting-sort scatter. Per-block LDS ranks + one cursor atomic per bucket
// per block -> contiguous runs. edata[pos] = (p0,p1,p2, bitcast(col));
// rpos_arr[pos] = rstart[row] + rrank[e]  (row-sorted message slot).
// All global writes coalesced; only 27 cursor atomics per block.
// ---------------------------------------------------------------------------
#define SCPER 4
__global__ __launch_bounds__(256) void bucket_scatter(const float* __restrict__ pseudo,
                                                      const int* __restrict__ ei,
                                                      const int* __restrict__ rrank,
                                                      const int* __restrict__ rstart,
                                                      int* __restrict__ cursor,
                                                      float4* __restrict__ edata,
                                                      int* __restrict__ rpos_arr) {
  __shared__ int lh[27];
  __shared__ int bb[27];
  if (threadIdx.x < 27) lh[threadIdx.x] = 0;
  __syncthreads();
  const int e0 = blockIdx.x * 256 * SCPER;
  float p0[SCPER], p1[SCPER], p2[SCPER];
  int rk[SCPER], bq[SCPER];
#pragma unroll
  for (int i = 0; i < SCPER; ++i) {
    int e = e0 + i * 256 + threadIdx.x;
    bq[i] = -1;
    if (e < EE) {
      float a0 = pseudo[e * 3 + 0];
      float a1 = pseudo[e * 3 + 1];
      float a2 = pseudo[e * 3 + 2];
      int b0 = (int)fminf(fmaxf(floorf(a0 * 3.0f), 0.0f), 2.0f);
      int b1 = (int)fminf(fmaxf(floorf(a1 * 3.0f), 0.0f), 2.0f);
      int b2 = (int)fminf(fmaxf(floorf(a2 * 3.0f), 0.0f), 2.0f);
      int q = b0 + 3 * b1 + 9 * b2;
      p0[i] = a0; p1[i] = a1; p2[i] = a2;
      rk[i] = atomicAdd(&lh[q], 1);
      bq[i] = q;
    }
  }
  __syncthreads();
  if (threadIdx.x < 27) bb[threadIdx.x] = atomicAdd(&cursor[threadIdx.x], lh[threadIdx.x]);
  __syncthreads();
#pragma unroll
  for (int i = 0; i < SCPER; ++i) {
    if (bq[i] < 0) continue;
    int e = e0 + i * 256 + threadIdx.x;
    int pos = bb[bq[i]] + rk[i];
    int row = ei[e], col = ei[EE + e];
    edata[pos] = make_float4(p0[i], p1[i], p2[i], __int_as_float(col));
    rpos_arr[pos] = rstart[row] + rrank[e];        // non-atomic L2-hit read
  }
}

// ---------------------------------------------------------------------------
// Bucketed MFMA, atomic-free. Per group of 16 edges:
//   A-row m: bf16 f[col_m] (unscaled); per s: d = mfma(A, W[base+off_s], 0);
//   msg row += w_s(edge) * d  (fp32, weights via __shfl from lane edge).
// Store at the edge's ROW-SORTED slot: msg_u32[rpos*16 + och] packs channels
// (o=och lo, o=och+16 hi); each edge's 16 u32 = exactly one 64 B line ->
// scattered full-line stores, no amplification, and gather becomes coalesced.
// Next-group edata/rpos/A-frag prefetched to hide gather latency.
// D layout (m89-verified): col=lane&15, row=(lane>>4)*4+reg.
// ---------------------------------------------------------------------------
__global__ __launch_bounds__(256) void edge_mfma_nw(const float4* __restrict__ edata,
                                                    const int* __restrict__ rpos_arr,
                                                    const short* __restrict__ fbh,
                                                    const short* __restrict__ Wb,
                                                    const int* __restrict__ bstart,
                                                    unsigned* __restrict__ msg) {
  const int q   = blockIdx.x / BPB;
  const int sub = blockIdx.x % BPB;
  const int l   = threadIdx.x & 63;
  const int wid = threadIdx.x >> 6;

  const int start = bstart[q];
  const int end   = bstart[q + 1];
  const int nE    = end - start;
  if (nE <= 0) return;
  const int ngroups = (nE + 15) >> 4;

  const int b0 = q % 3, b1 = (q / 3) % 3, b2 = q / 9;
  const int base = b0 + 4 * b1 + 16 * b2;
  const int ko[8] = {0, 1, 4, 5, 16, 17, 20, 21};

  s16x8 bf[8][2];                                  // bucket's B frags, 64 VGPRs
#pragma unroll
  for (int s = 0; s < 8; ++s) {
    int kmat = base + ko[s];
#pragma unroll
    for (int oh = 0; oh < 2; ++oh)
      bf[s][oh] = ((const s16x8*)Wb)[(kmat * 2 + oh) * 64 + l];
  }

  const int m   = l & 15;         // A-row edge-in-group for this lane
  const int och = l & 15;         // D column within tile
  const int eb  = (l >> 4) * 4;   // first D-row edge in this lane's quarter
  const int kq  = l >> 4;
  const int stride = BPB * 4;

  int g = sub * 4 + wid;
  if (g >= ngroups) return;

  int idx = start + g * 16 + m;
  int cidx = idx < end ? idx : start;
  float4 ed = edata[cidx];
  int    rp = rpos_arr[cidx];
  s16x8  af = ((const s16x8*)fbh)[(size_t)__float_as_int(ed.w) * 4 + kq];

  while (true) {
    const int gn = g + stride;
    const bool more = gn < ngroups;
    int idxn = start + gn * 16 + m;
    int cidxn = (more && idxn < end) ? idxn : start;
    float4 edn = edata[cidxn];                     // prefetch
    int    rpn = rpos_arr[cidxn];

    // spline weights of this lane's A-edge (garbage for tail lanes is fine:
    // tail rows' stores are guarded below, MFMA rows are independent)
    float f0 = ed.x * 3.0f - (float)b0;
    float f1 = ed.y * 3.0f - (float)b1;
    float f2 = ed.z * 3.0f - (float)b2;
    float g0 = 1.0f - f0, g1c = 1.0f - f1, g2c = 1.0f - f2;
    float w8[8];
    w8[0] = g0 * g1c * g2c; w8[1] = f0 * g1c * g2c;
    w8[2] = g0 * f1 * g2c;  w8[3] = f0 * f1 * g2c;
    w8[4] = g0 * g1c * f2;  w8[5] = f0 * g1c * f2;
    w8[6] = g0 * f1 * f2;   w8[7] = f0 * f1 * f2;

    // prefetch next A-frag (hides fbh gather under MFMA+store)
    s16x8 afn = ((const s16x8*)fbh)[(size_t)__float_as_int(edn.w) * 4 + kq];

    f32x4 acc0 = {0.f, 0.f, 0.f, 0.f}, acc1 = {0.f, 0.f, 0.f, 0.f};
#pragma unroll
    for (int s = 0; s < 8; ++s) {
      f32x4 d0 = __builtin_amdgcn_mfma_f32_16x16x32_bf16(af, bf[s][0],
                   (f32x4){0.f, 0.f, 0.f, 0.f}, 0, 0, 0);
      f32x4 d1 = __builtin_amdgcn_mfma_f32_16x16x32_bf16(af, bf[s][1],
                   (f32x4){0.f, 0.f, 0.f, 0.f}, 0, 0, 0);
#pragma unroll
      for (int r = 0; r < 4; ++r) {
        float wsr = __shfl(w8[s], eb + r, 64);
        acc0[r] += wsr * d0[r];
        acc1[r] += wsr * d1[r];
      }
    }

#pragma unroll
    for (int r = 0; r < 4; ++r) {
      int ridx = g * 16 + eb + r;                  // bucket-local row
      int rps  = __shfl(rp, eb + r, 64);           // row-sorted slot of edge
      if (ridx < nE) {
        unsigned lo = (unsigned)(unsigned short)f2bs(acc0[r]);
        unsigned hi = (unsigned)(unsigned short)f2bs(acc1[r]);
        msg[(size_t)rps * 16 + och] = lo | (hi << 16);
      }
    }

    if (!more) break;
    g = gn; ed = edn; af = afn; rp = rpn;
  }
}

// ---------------------------------------------------------------------------
// Per-node gather: 16 lanes/node. Messages for node n are CONTIGUOUS slots
// [rstart[n], rstart[n+1]) -> fully coalesced stream. Sum bf16 in fp32,
// divide by deg, add bias. Single writer, no atomics, no indirection.
// Lane j holds channels o=j (lo halves) and o=j+16 (hi halves).
// ---------------------------------------------------------------------------
__global__ __launch_bounds__(256) void gather_out(const unsigned* __restrict__ msg,
                                                  const int* __restrict__ rstart,
                                                  const float* __restrict__ bias,
                                                  float* __restrict__ out) {
  int n = (blockIdx.x * 256 + threadIdx.x) >> 4;   // node
  int j = threadIdx.x & 15;
  if (n >= NN) return;
  int s = rstart[n], e = rstart[n + 1];
  int cnt = e - s;
  const unsigned* mp = msg + (size_t)s * 16 + j;
  float s0 = 0.f, s1 = 0.f;
  int i = 0;
  for (; i + 4 <= cnt; i += 4) {                   // unroll-4 for MLP
    unsigned uA = mp[(size_t)(i + 0) * 16];
    unsigned uB = mp[(size_t)(i + 1) * 16];
    unsigned uC = mp[(size_t)(i + 2) * 16];
    unsigned uD = mp[(size_t)(i + 3) * 16];
    s0 += __uint_as_float(uA << 16); s1 += __uint_as_float(uA & 0xFFFF0000u);
    s0 += __uint_as_float(uB << 16); s1 += __uint_as_float(uB & 0xFFFF0000u);
    s0 += __uint_as_float(uC << 16); s1 += __uint_as_float(uC & 0xFFFF0000u);
    s0 += __uint_as_float(uD << 16); s1 += __uint_as_float(uD & 0xFFFF0000u);
  }
  for (; i < cnt; ++i) {
    unsigned u = mp[(size_t)i * 16];
    s0 += __uint_as_float(u << 16);
    s1 += __uint_as_float(u & 0xFFFF0000u);
  }
  float d = fmaxf((float)cnt, 1.0f);
  out[n * 32 + j]      = s0 / d + bias[j];
  out[n * 32 + 16 + j] = s1 / d + bias[16 + j];
}

// ---------------------------------------------------------------------------
// Fallback path (small workspace): direct per-edge compute + atomics.
// ---------------------------------------------------------------------------
static __device__ __forceinline__ void spline_basis(const float* __restrict__ pseudo,
                                                    int e, float w[8], int& base) {
  float v0 = pseudo[e * 3 + 0] * 3.0f;
  float v1 = pseudo[e * 3 + 1] * 3.0f;
  float v2 = pseudo[e * 3 + 2] * 3.0f;
  float b0 = fmaxf(fminf(floorf(v0), 2.0f), 0.0f);
  float b1 = fmaxf(fminf(floorf(v1), 2.0f), 0.0f);
  float b2 = fmaxf(fminf(floorf(v2), 2.0f), 0.0f);
  float f0 = v0 - b0, f1 = v1 - b1, f2 = v2 - b2;
  float g0 = 1.0f - f0, g1 = 1.0f - f1, g2 = 1.0f - f2;
  base = (int)b0 + 4 * (int)b1 + 16 * (int)b2;
  w[0] = g0 * g1 * g2; w[1] = f0 * g1 * g2;
  w[2] = g0 * f1 * g2; w[3] = f0 * f1 * g2;
  w[4] = g0 * g1 * f2; w[5] = f0 * g1 * f2;
  w[6] = g0 * f1 * f2; w[7] = f0 * f1 * f2;
}

__global__ __launch_bounds__(256) void edge_direct(const float* __restrict__ pseudo,
                                                   const int* __restrict__ ei,
                                                   const float* __restrict__ f,
                                                   const float* __restrict__ W,
                                                   float* __restrict__ acc,
                                                   float* __restrict__ deg) {
  const int tid = blockIdx.x * 256 + threadIdx.x;
  const int e = tid >> 5;
  const int o = tid & 31;
  if (e >= EE) return;
  const int row = ei[e];
  const int col = ei[EE + e];
  float w[8]; int base;
  spline_basis(pseudo, e, w, base);
  const float myf = f[col * 32 + o];
  float a = 0.0f;
  for (int i = 0; i < 32; ++i) {
    float fi = __shfl(myf, i, 32);
    float wsum = 0.0f;
#pragma unroll
    for (int s = 0; s < 8; ++s)
      wsum += w[s] * W[(size_t)(base + kOffs[s]) * 1024 + i * 32 + o];
    a += fi * wsum;
  }
  atomicAdd(acc + (size_t)row * 32 + o, a);
  if (o == 0) atomicAdd(deg + row, 1.0f);
}

__global__ __launch_bounds__(256) void finalize(const float* __restrict__ acc,
                                                const float* __restrict__ deg,
                                                const float* __restrict__ bias,
                                                float* __restrict__ out) {
  int tid = blockIdx.x * 256 + threadIdx.x;
  if (tid >= NN * 32) return;
  int n = tid >> 5, o = tid & 31;
  float d = fmaxf(deg[n], 1.0f);
  out[tid] = acc[tid] / d + bias[o];
}

extern "C" void kernel_launch(void* const* d_in, const int* in_sizes, int n_in,
                              void* d_out, int out_size, void* d_ws, size_t ws_size,
                              hipStream_t stream) {
  const float* f      = (const float*)d_in[0];
  const float* pseudo = (const float*)d_in[1];
  const float* W      = (const float*)d_in[2];
  const float* bias   = (const float*)d_in[3];
  const int*   ei     = (const int*)d_in[4];
  float* out = (float*)d_out;

  // Workspace layout (~144.5 MB total; big path verified to run in round 4)
  constexpr size_t HIST_OFF  = 0;                      // 27 ints
  constexpr size_t DEGI_OFF  = 128;                    // NN ints
  constexpr size_t ZERO_SZ   = 128 + (size_t)NN * 4;   // memset: hist + degi
  constexpr size_t BST_OFF   = 200192;                 // 28 ints
  constexpr size_t CUR_OFF   = BST_OFF + 128;          // 27 ints
  constexpr size_t RST_OFF   = 200448;                 // NN+1 ints
  constexpr size_t RRANK_OFF = 400512;                 // EE ints
  constexpr size_t ED_OFF    = RRANK_OFF + (size_t)EE * 4;   // 6,800,512 (16B ok)
  constexpr size_t RPOS_OFF  = ED_OFF + (size_t)EE * 16;     // 32,400,512
  constexpr size_t MSG_OFF   = RPOS_OFF + (size_t)EE * 4;    // 38,800,512
  constexpr size_t FBH_OFF   = MSG_OFF + (size_t)EE * 64;    // 141,200,512
  constexpr size_t WB_OFF    = FBH_OFF + (size_t)NN * 64;    // 144,400,512
  constexpr size_t TOTAL     = WB_OFF + 128 * 64 * 8 * 2;    // 144,531,584

  char* ws = (char*)d_ws;

  if (ws_size >= TOTAL) {
    int*      hist  = (int*)(ws + HIST_OFF);
    int*      degi  = (int*)(ws + DEGI_OFF);
    int*      bst   = (int*)(ws + BST_OFF);
    int*      cur   = (int*)(ws + CUR_OFF);
    int*      rst   = (int*)(ws + RST_OFF);
    int*      rrank = (int*)(ws + RRANK_OFF);
    float4*   edata = (float4*)(ws + ED_OFF);
    int*      rpos  = (int*)(ws + RPOS_OFF);
    unsigned* msg   = (unsigned*)(ws + MSG_OFF);
    short*    fbh   = (short*)(ws + FBH_OFF);
    short*    Wb    = (short*)(ws + WB_OFF);

    hipMemsetAsync(ws, 0, ZERO_SZ, stream);
    prep<<<PREP_BLOCKS, 256, 0, stream>>>(W, f, pseudo, ei, Wb, fbh, hist, degi, rrank);
    scan27<<<1, 64, 0, stream>>>(hist, bst, cur);
    scan_rows<<<1, 1024, 0, stream>>>(degi, rst);
    bucket_scatter<<<(EE + 256 * SCPER - 1) / (256 * SCPER), 256, 0, stream>>>(
        pseudo, ei, rrank, rst, cur, edata, rpos);
    edge_mfma_nw<<<27 * BPB, 256, 0, stream>>>(edata, rpos, fbh, Wb, bst, msg);
    gather_out<<<(NN * 16 + 255) / 256, 256, 0, stream>>>(msg, rst, bias, out);
  } else {
    constexpr size_t ACC_SZ = (size_t)NN * 32 * 4;
    float* acc = (float*)ws;
    float* deg = (float*)(ws + ACC_SZ);
    hipMemsetAsync(acc, 0, ACC_SZ + (size_t)NN * 4, stream);
    edge_direct<<<(EE * 32) / 256, 256, 0, stream>>>(pseudo, ei, f, W, acc, deg);
    finalize<<<(NN * 32) / 256, 256, 0, stream>>>(acc, deg, bias, out);
  }
}

// Round 6
// 320.550 us; speedup vs baseline: 1.4749x; 1.0513x over previous
//
#include <hip/hip_runtime.h>
#include <hip/hip_bf16.h>

// Problem constants: N=50000, E=1600000, D=3, IN=32, OUT=32, KS=4, K=64, S=8
// Atomic-light, indirection-free structure:
//   prep: pack W/f to bf16, bucket-hist (27), row-degree hist whose atomic
//         RETURN VALUE is saved as rrank[e] (within-row rank, free).
//   scan_all: 27-bucket scan (wave 15) + 50K row scan (whole block).
//   bucket_scatter: counting-sort edges by spline base; rpos_arr[bucketpos] =
//         rstart[row] + rrank[e]  (no atomics, coalesced writes).
//   edge_mfma_nw: per-bucket MFMA with SWAPPED operands:
//         D = mfma(Wb, fbh) -> D[row=o_channel][col=edge]; each lane's D
//         column is its OWN edge, so spline weights + rpos are lane-local
//         (no cross-lane ops at all) and the store is one dwordx4 per lane
//         at the edge's ROW-SORTED slot (64 B line per edge).
//   gather_out: per node, messages are CONTIGUOUS [rstart[n],rstart[n+1]) ->
//         fully coalesced streaming sum, /deg, +bias.
#define NN 50000
#define EE 1600000
#define BPB 64       // blocks per bucket in edge_mfma_nw

typedef __attribute__((ext_vector_type(8))) short  s16x8;   // 8 bf16 (4 VGPRs)
typedef __attribute__((ext_vector_type(4))) float  f32x4;   // MFMA C/D frag

static __device__ __forceinline__ short f2bs(float x) {
  __hip_bfloat16 h = __float2bfloat16(x);
  short s; __builtin_memcpy(&s, &h, 2); return s;
}

__constant__ int kOffs[8] = {0, 1, 4, 5, 16, 17, 20, 21};

// ---------------------------------------------------------------------------
// prep (fused): blocks [0,32) conv_w ; [32,160) pack_f ; [160,416) hists.
// conv_w: W fp32 [k][i][o] -> bf16 frag layout (tile t=kmat*2+oh; frag elem
// (t,l,j) = W[kmat][(l>>4)*8+j][oh*16+(l&15)]).  Read as an MFMA A-frag this
// is W^T (A[o][k]); read as a B-frag it is W (B[k][o]) — same bytes.
// pack_f: f fp32 [N][32] -> bf16 [N][32] (3.2 MB; the per-edge MFMA operand).
// hists: bucket q = b0+3*b1+9*b2 (27 bins, LDS-staged) + row degree atomic
//        whose return value is the edge's within-row rank -> rrank[e].
// ---------------------------------------------------------------------------
#define PREP_BLOCKS 416
__global__ __launch_bounds__(256) void prep(const float* __restrict__ W,
                                            const float* __restrict__ f,
                                            const float* __restrict__ pseudo,
                                            const int* __restrict__ ei,
                                            short* __restrict__ Wb,
                                            short* __restrict__ fbh,
                                            int* __restrict__ hist,
                                            int* __restrict__ degi,
                                            int* __restrict__ rrank) {
  const int b = blockIdx.x;
  if (b < 32) {
    int tid = b * 256 + threadIdx.x;               // 8192 threads, one frag each
    int t = tid >> 6, l = tid & 63;
    int c = t * 16 + (l & 15);
    int k0 = (l >> 4) * 8;
    s16x8 frag;
#pragma unroll
    for (int j = 0; j < 8; ++j)
      frag[j] = f2bs(W[(c >> 5) * 1024 + (k0 + j) * 32 + (c & 31)]);
    ((s16x8*)Wb)[tid] = frag;
  } else if (b < 160) {
    for (int tid = (b - 32) * 256 + threadIdx.x; tid < NN * 32 / 8; tid += 128 * 256) {
      const f32x4* fp = (const f32x4*)f + (size_t)tid * 2;
      f32x4 a = fp[0], c = fp[1];
      s16x8 o;
#pragma unroll
      for (int j = 0; j < 4; ++j) { o[j] = f2bs(a[j]); o[4 + j] = f2bs(c[j]); }
      ((s16x8*)fbh)[tid] = o;
    }
  } else {
    __shared__ int lh[27];
    if (threadIdx.x < 27) lh[threadIdx.x] = 0;
    __syncthreads();
    for (int e = (b - 160) * 256 + threadIdx.x; e < EE; e += 256 * 256) {
      float v0 = pseudo[e * 3 + 0] * 3.0f;
      float v1 = pseudo[e * 3 + 1] * 3.0f;
      float v2 = pseudo[e * 3 + 2] * 3.0f;
      int b0 = (int)fminf(fmaxf(floorf(v0), 0.0f), 2.0f);
      int b1 = (int)fminf(fmaxf(floorf(v1), 0.0f), 2.0f);
      int b2 = (int)fminf(fmaxf(floorf(v2), 0.0f), 2.0f);
      atomicAdd(&lh[b0 + 3 * b1 + 9 * b2], 1);
      rrank[e] = atomicAdd(&degi[ei[e]], 1);       // rank = free atomic return
    }
    __syncthreads();
    if (threadIdx.x < 27) atomicAdd(hist + threadIdx.x, lh[threadIdx.x]);
  }
}

// ---------------------------------------------------------------------------
// scan_all (grid=1, 1024 threads):
//   wave 15: exclusive scan of 27 bucket counts (shfl prefix, no barriers).
//   all waves: exclusive scan of degi[50000] -> rstart[0..NN] (uniform
//   barriers; wave 15's extra pre-work doesn't break barrier uniformity).
// ---------------------------------------------------------------------------
__global__ __launch_bounds__(1024) void scan_all(const int* __restrict__ hist,
                                                 const int* __restrict__ degi,
                                                 int* __restrict__ bstart,
                                                 int* __restrict__ cursor,
                                                 int* __restrict__ rstart) {
  const int lane = threadIdx.x & 63;
  const int wid  = threadIdx.x >> 6;
  if (wid == 15) {                                 // 27-bucket scan
    int v = (lane < 27) ? hist[lane] : 0;
    int x = v;
#pragma unroll
    for (int d = 1; d < 32; d <<= 1) {
      int y = __shfl_up(x, d, 64);
      if (lane >= d) x += y;
    }
    if (lane < 27) { bstart[lane] = x - v; cursor[lane] = x - v; }
    if (lane == 26) bstart[27] = x;                // total = EE
  }
  __shared__ int carry;
  __shared__ int tot;
  __shared__ int wsum[16];
  if (threadIdx.x == 0) carry = 0;
  __syncthreads();
  for (int c0 = 0; c0 < NN; c0 += 1024) {
    int i = c0 + threadIdx.x;
    int v = (i < NN) ? degi[i] : 0;
    int x = v;
#pragma unroll
    for (int d = 1; d < 64; d <<= 1) {
      int y = __shfl_up(x, d, 64);
      if (lane >= d) x += y;
    }
    if (lane == 63) wsum[wid] = x;
    __syncthreads();                               // wsum ready
    if (threadIdx.x == 0) {
      int run = 0;
#pragma unroll
      for (int w = 0; w < 16; ++w) { int t = wsum[w]; wsum[w] = run; run += t; }
      tot = run;
    }
    __syncthreads();                               // wsum exclusive, tot ready
    int excl = carry + wsum[wid] + (x - v);
    if (i < NN) rstart[i] = excl;
    __syncthreads();                               // all reads of carry done
    if (threadIdx.x == 0) carry += tot;
    __syncthreads();
  }
  if (threadIdx.x == 0) rstart[NN] = carry;        // == EE
}

// ---------------------------------------------------------------------------
// Counting-sort scatter. Per-block LDS ranks + one cursor atomic per bucket
// per block -> contiguous runs. edata[pos] = (p0,p1,p2, bitcast(col));
// rpos_arr[pos] = rstart[row] + rrank[e]  (row-sorted message slot).
// All global writes coalesced; only 27 cursor atomics per block.
// ---------------------------------------------------------------------------
#define SCPER 2
__global__ __launch_bounds__(256) void bucket_scatter(const float* __restrict__ pseudo,
                                                      const int* __restrict__ ei,
                                                      const int* __restrict__ rrank,
                                                      const int* __restrict__ rstart,
                                                      int* __restrict__ cursor,
                                                      float4* __restrict__ edata,
                                                      int* __restrict__ rpos_arr) {
  __shared__ int lh[27];
  __shared__ int bb[27];
  if (threadIdx.x < 27) lh[threadIdx.x] = 0;
  __syncthreads();
  const int e0 = blockIdx.x * 256 * SCPER;
  float p0[SCPER], p1[SCPER], p2[SCPER];
  int rk[SCPER], bq[SCPER];
#pragma unroll
  for (int i = 0; i < SCPER; ++i) {
    int e = e0 + i * 256 + threadIdx.x;
    bq[i] = -1;
    if (e < EE) {
      float a0 = pseudo[e * 3 + 0];
      float a1 = pseudo[e * 3 + 1];
      float a2 = pseudo[e * 3 + 2];
      int b0 = (int)fminf(fmaxf(floorf(a0 * 3.0f), 0.0f), 2.0f);
      int b1 = (int)fminf(fmaxf(floorf(a1 * 3.0f), 0.0f), 2.0f);
      int b2 = (int)fminf(fmaxf(floorf(a2 * 3.0f), 0.0f), 2.0f);
      int q = b0 + 3 * b1 + 9 * b2;
      p0[i] = a0; p1[i] = a1; p2[i] = a2;
      rk[i] = atomicAdd(&lh[q], 1);
      bq[i] = q;
    }
  }
  __syncthreads();
  if (threadIdx.x < 27) bb[threadIdx.x] = atomicAdd(&cursor[threadIdx.x], lh[threadIdx.x]);
  __syncthreads();
#pragma unroll
  for (int i = 0; i < SCPER; ++i) {
    if (bq[i] < 0) continue;
    int e = e0 + i * 256 + threadIdx.x;
    int pos = bb[bq[i]] + rk[i];
    int row = ei[e], col = ei[EE + e];
    edata[pos] = make_float4(p0[i], p1[i], p2[i], __int_as_float(col));
    rpos_arr[pos] = rstart[row] + rrank[e];        // non-atomic L2-hit read
  }
}

// ---------------------------------------------------------------------------
// Bucketed MFMA, atomic-free, SWAPPED OPERANDS. Per group of 16 edges:
//   D = mfma(A=W^T tile (Wb frag), B=f^T (fbh frag), 0)
//   -> D[row=(l>>4)*4+r = o-channel][col=l&15 = edge]  (m89 layout).
// Lane l owns edge m=l&15: it loads edata/rpos for m, supplies the B k-chunk
// kq=l>>4 of m's features, and receives D channels o=kq*4+r of edge m.
//   acc += w_s(own edge) * d_s   -- fp32, exact weights, NO cross-lane ops.
// Store: ONE dwordx4 per lane: msg4[rp*4+kq] = {pk(o,o+16)}_{r=0..3}
// (channel-pair convention matches gather_out: word o' = (ch o', ch o'+16)).
// Next-group edata/rpos/B-frag prefetched to hide gather latency.
// ---------------------------------------------------------------------------
__global__ __launch_bounds__(256) void edge_mfma_nw(const float4* __restrict__ edata,
                                                    const int* __restrict__ rpos_arr,
                                                    const short* __restrict__ fbh,
                                                    const short* __restrict__ Wb,
                                                    const int* __restrict__ bstart,
                                                    uint4* __restrict__ msg4) {
  const int q   = blockIdx.x / BPB;
  const int sub = blockIdx.x % BPB;
  const int l   = threadIdx.x & 63;
  const int wid = threadIdx.x >> 6;

  const int start = bstart[q];
  const int end   = bstart[q + 1];
  const int nE    = end - start;
  if (nE <= 0) return;
  const int ngroups = (nE + 15) >> 4;

  const int b0 = q % 3, b1 = (q / 3) % 3, b2 = q / 9;
  const int base = b0 + 4 * b1 + 16 * b2;
  const int ko[8] = {0, 1, 4, 5, 16, 17, 20, 21};

  s16x8 bf[8][2];                                  // bucket's W frags, 64 VGPRs
#pragma unroll
  for (int s = 0; s < 8; ++s) {
    int kmat = base + ko[s];
#pragma unroll
    for (int oh = 0; oh < 2; ++oh)
      bf[s][oh] = ((const s16x8*)Wb)[(kmat * 2 + oh) * 64 + l];
  }

  const int m   = l & 15;         // edge-in-group OWNED by this lane
  const int kq  = l >> 4;         // B k-chunk / D o-quarter
  const int stride = BPB * 4;

  int g = sub * 4 + wid;
  if (g >= ngroups) return;

  int idx = start + g * 16 + m;
  int cidx = idx < end ? idx : start;
  float4 ed = edata[cidx];
  int    rp = rpos_arr[cidx];
  s16x8  af = ((const s16x8*)fbh)[(size_t)__float_as_int(ed.w) * 4 + kq];

  while (true) {
    const int gn = g + stride;
    const bool more = gn < ngroups;
    int idxn = start + gn * 16 + m;
    int cidxn = (more && idxn < end) ? idxn : start;
    float4 edn = edata[cidxn];                     // prefetch
    int    rpn = rpos_arr[cidxn];

    // spline weights of this lane's OWN edge (tail lanes: garbage is fine,
    // their store is skipped; garbage B columns stay in garbage D columns)
    float f0 = ed.x * 3.0f - (float)b0;
    float f1 = ed.y * 3.0f - (float)b1;
    float f2 = ed.z * 3.0f - (float)b2;
    float g0 = 1.0f - f0, g1c = 1.0f - f1, g2c = 1.0f - f2;
    float w8[8];
    w8[0] = g0 * g1c * g2c; w8[1] = f0 * g1c * g2c;
    w8[2] = g0 * f1 * g2c;  w8[3] = f0 * f1 * g2c;
    w8[4] = g0 * g1c * f2;  w8[5] = f0 * g1c * f2;
    w8[6] = g0 * f1 * f2;   w8[7] = f0 * f1 * f2;

    // prefetch next B-frag (hides fbh gather under MFMA+store)
    s16x8 afn = ((const s16x8*)fbh)[(size_t)__float_as_int(edn.w) * 4 + kq];

    f32x4 acc0 = {0.f, 0.f, 0.f, 0.f}, acc1 = {0.f, 0.f, 0.f, 0.f};
#pragma unroll
    for (int s = 0; s < 8; ++s) {
      f32x4 d0 = __builtin_amdgcn_mfma_f32_16x16x32_bf16(bf[s][0], af,
                   (f32x4){0.f, 0.f, 0.f, 0.f}, 0, 0, 0);   // o = 0..15
      f32x4 d1 = __builtin_amdgcn_mfma_f32_16x16x32_bf16(bf[s][1], af,
                   (f32x4){0.f, 0.f, 0.f, 0.f}, 0, 0, 0);   // o = 16..31
      float ws = w8[s];
#pragma unroll
      for (int r = 0; r < 4; ++r) {
        acc0[r] += ws * d0[r];
        acc1[r] += ws * d1[r];
      }
    }

    if (g * 16 + m < nE) {                         // lane's own edge valid?
      uint4 pk;
      pk.x = (unsigned)(unsigned short)f2bs(acc0[0]) |
             ((unsigned)(unsigned short)f2bs(acc1[0]) << 16);
      pk.y = (unsigned)(unsigned short)f2bs(acc0[1]) |
             ((unsigned)(unsigned short)f2bs(acc1[1]) << 16);
      pk.z = (unsigned)(unsigned short)f2bs(acc0[2]) |
             ((unsigned)(unsigned short)f2bs(acc1[2]) << 16);
      pk.w = (unsigned)(unsigned short)f2bs(acc0[3]) |
             ((unsigned)(unsigned short)f2bs(acc1[3]) << 16);
      msg4[(size_t)rp * 4 + kq] = pk;              // one 16 B store per lane
    }

    if (!more) break;
    g = gn; ed = edn; af = afn; rp = rpn;
  }
}

// ---------------------------------------------------------------------------
// Per-node gather: 16 lanes/node. Messages for node n are CONTIGUOUS slots
// [rstart[n], rstart[n+1]) -> fully coalesced stream. Sum bf16 in fp32,
// divide by deg, add bias. Single writer, no atomics, no indirection.
// Lane j holds channels o=j (lo halves) and o=j+16 (hi halves).
// ---------------------------------------------------------------------------
__global__ __launch_bounds__(256) void gather_out(const unsigned* __restrict__ msg,
                                                  const int* __restrict__ rstart,
                                                  const float* __restrict__ bias,
                                                  float* __restrict__ out) {
  int n = (blockIdx.x * 256 + threadIdx.x) >> 4;   // node
  int j = threadIdx.x & 15;
  if (n >= NN) return;
  int s = rstart[n], e = rstart[n + 1];
  int cnt = e - s;
  const unsigned* mp = msg + (size_t)s * 16 + j;
  float s0 = 0.f, s1 = 0.f;
  int i = 0;
  for (; i + 4 <= cnt; i += 4) {                   // unroll-4 for MLP
    unsigned uA = mp[(size_t)(i + 0) * 16];
    unsigned uB = mp[(size_t)(i + 1) * 16];
    unsigned uC = mp[(size_t)(i + 2) * 16];
    unsigned uD = mp[(size_t)(i + 3) * 16];
    s0 += __uint_as_float(uA << 16); s1 += __uint_as_float(uA & 0xFFFF0000u);
    s0 += __uint_as_float(uB << 16); s1 += __uint_as_float(uB & 0xFFFF0000u);
    s0 += __uint_as_float(uC << 16); s1 += __uint_as_float(uC & 0xFFFF0000u);
    s0 += __uint_as_float(uD << 16); s1 += __uint_as_float(uD & 0xFFFF0000u);
  }
  for (; i < cnt; ++i) {
    unsigned u = mp[(size_t)i * 16];
    s0 += __uint_as_float(u << 16);
    s1 += __uint_as_float(u & 0xFFFF0000u);
  }
  float d = fmaxf((float)cnt, 1.0f);
  out[n * 32 + j]      = s0 / d + bias[j];
  out[n * 32 + 16 + j] = s1 / d + bias[16 + j];
}

// ---------------------------------------------------------------------------
// Fallback path (small workspace): direct per-edge compute + atomics.
// ---------------------------------------------------------------------------
static __device__ __forceinline__ void spline_basis(const float* __restrict__ pseudo,
                                                    int e, float w[8], int& base) {
  float v0 = pseudo[e * 3 + 0] * 3.0f;
  float v1 = pseudo[e * 3 + 1] * 3.0f;
  float v2 = pseudo[e * 3 + 2] * 3.0f;
  float b0 = fmaxf(fminf(floorf(v0), 2.0f), 0.0f);
  float b1 = fmaxf(fminf(floorf(v1), 2.0f), 0.0f);
  float b2 = fmaxf(fminf(floorf(v2), 2.0f), 0.0f);
  float f0 = v0 - b0, f1 = v1 - b1, f2 = v2 - b2;
  float g0 = 1.0f - f0, g1 = 1.0f - f1, g2 = 1.0f - f2;
  base = (int)b0 + 4 * (int)b1 + 16 * (int)b2;
  w[0] = g0 * g1 * g2; w[1] = f0 * g1 * g2;
  w[2] = g0 * f1 * g2; w[3] = f0 * f1 * g2;
  w[4] = g0 * g1 * f2; w[5] = f0 * g1 * f2;
  w[6] = g0 * f1 * f2; w[7] = f0 * f1 * f2;
}

__global__ __launch_bounds__(256) void edge_direct(const float* __restrict__ pseudo,
                                                   const int* __restrict__ ei,
                                                   const float* __restrict__ f,
                                                   const float* __restrict__ W,
                                                   float* __restrict__ acc,
                                                   float* __restrict__ deg) {
  const int tid = blockIdx.x * 256 + threadIdx.x;
  const int e = tid >> 5;
  const int o = tid & 31;
  if (e >= EE) return;
  const int row = ei[e];
  const int col = ei[EE + e];
  float w[8]; int base;
  spline_basis(pseudo, e, w, base);
  const float myf = f[col * 32 + o];
  float a = 0.0f;
  for (int i = 0; i < 32; ++i) {
    float fi = __shfl(myf, i, 32);
    float wsum = 0.0f;
#pragma unroll
    for (int s = 0; s < 8; ++s)
      wsum += w[s] * W[(size_t)(base + kOffs[s]) * 1024 + i * 32 + o];
    a += fi * wsum;
  }
  atomicAdd(acc + (size_t)row * 32 + o, a);
  if (o == 0) atomicAdd(deg + row, 1.0f);
}

__global__ __launch_bounds__(256) void finalize(const float* __restrict__ acc,
                                                const float* __restrict__ deg,
                                                const float* __restrict__ bias,
                                                float* __restrict__ out) {
  int tid = blockIdx.x * 256 + threadIdx.x;
  if (tid >= NN * 32) return;
  int n = tid >> 5, o = tid & 31;
  float d = fmaxf(deg[n], 1.0f);
  out[tid] = acc[tid] / d + bias[o];
}

extern "C" void kernel_launch(void* const* d_in, const int* in_sizes, int n_in,
                              void* d_out, int out_size, void* d_ws, size_t ws_size,
                              hipStream_t stream) {
  const float* f      = (const float*)d_in[0];
  const float* pseudo = (const float*)d_in[1];
  const float* W      = (const float*)d_in[2];
  const float* bias   = (const float*)d_in[3];
  const int*   ei     = (const int*)d_in[4];
  float* out = (float*)d_out;

  // Workspace layout (~144.5 MB total; big path verified in rounds 4/5)
  constexpr size_t HIST_OFF  = 0;                      // 27 ints
  constexpr size_t DEGI_OFF  = 128;                    // NN ints
  constexpr size_t ZERO_SZ   = 128 + (size_t)NN * 4;   // memset: hist + degi
  constexpr size_t BST_OFF   = 200192;                 // 28 ints
  constexpr size_t CUR_OFF   = BST_OFF + 128;          // 27 ints
  constexpr size_t RST_OFF   = 200448;                 // NN+1 ints
  constexpr size_t RRANK_OFF = 400512;                 // EE ints
  constexpr size_t ED_OFF    = RRANK_OFF + (size_t)EE * 4;   // 6,800,512 (16B ok)
  constexpr size_t RPOS_OFF  = ED_OFF + (size_t)EE * 16;     // 32,400,512
  constexpr size_t MSG_OFF   = RPOS_OFF + (size_t)EE * 4;    // 38,800,512 (16B ok)
  constexpr size_t FBH_OFF   = MSG_OFF + (size_t)EE * 64;    // 141,200,512
  constexpr size_t WB_OFF    = FBH_OFF + (size_t)NN * 64;    // 144,400,512
  constexpr size_t TOTAL     = WB_OFF + 128 * 64 * 8 * 2;    // 144,531,584

  char* ws = (char*)d_ws;

  if (ws_size >= TOTAL) {
    int*      hist  = (int*)(ws + HIST_OFF);
    int*      degi  = (int*)(ws + DEGI_OFF);
    int*      bst   = (int*)(ws + BST_OFF);
    int*      cur   = (int*)(ws + CUR_OFF);
    int*      rst   = (int*)(ws + RST_OFF);
    int*      rrank = (int*)(ws + RRANK_OFF);
    float4*   edata = (float4*)(ws + ED_OFF);
    int*      rpos  = (int*)(ws + RPOS_OFF);
    uint4*    msg4  = (uint4*)(ws + MSG_OFF);
    unsigned* msg   = (unsigned*)(ws + MSG_OFF);
    short*    fbh   = (short*)(ws + FBH_OFF);
    short*    Wb    = (short*)(ws + WB_OFF);

    hipMemsetAsync(ws, 0, ZERO_SZ, stream);
    prep<<<PREP_BLOCKS, 256, 0, stream>>>(W, f, pseudo, ei, Wb, fbh, hist, degi, rrank);
    scan_all<<<1, 1024, 0, stream>>>(hist, degi, bst, cur, rst);
    bucket_scatter<<<(EE + 256 * SCPER - 1) / (256 * SCPER), 256, 0, stream>>>(
        pseudo, ei, rrank, rst, cur, edata, rpos);
    edge_mfma_nw<<<27 * BPB, 256, 0, stream>>>(edata, rpos, fbh, Wb, bst, msg4);
    gather_out<<<(NN * 16 + 255) / 256, 256, 0, stream>>>(msg, rst, bias, out);
  } else {
    constexpr size_t ACC_SZ = (size_t)NN * 32 * 4;
    float* acc = (float*)ws;
    float* deg = (float*)(ws + ACC_SZ);
    hipMemsetAsync(acc, 0, ACC_SZ + (size_t)NN * 4, stream);
    edge_direct<<<(EE * 32) / 256, 256, 0, stream>>>(pseudo, ei, f, W, acc, deg);
    finalize<<<(NN * 32) / 256, 256, 0, stream>>>(acc, deg, bias, out);
  }
}

// Round 7
// 299.329 us; speedup vs baseline: 1.5794x; 1.0709x over previous
//
#include <hip/hip_runtime.h>
#include <hip/hip_bf16.h>

// Problem constants: N=50000, E=1600000, D=3, IN=32, OUT=32, KS=4, K=64, S=8
// Deterministic counting-sort structure (atomic-returns minimized):
//   prep: pack W/f to bf16; per-CHUNK 27-bin histogram -> blockhist matrix
//         (no global hist atomics); rrank[e] = degi row atomic return (only
//         remaining global atomic, 4/thread with ~24 waves/CU to hide it).
//   scan_combo: blk0 scans blockhist[27][NCHUNK] flat (bin-major => [q][0]
//         is bstart[q]); blk1 scans row degrees -> rstart (row-CSR).
//   bucket_scatter: 1 block = 1 chunk; base = pre-scanned blockhist[q][c];
//         LDS rank atomics only -> ZERO global atomics.
//   edge_mfma_nw: per-bucket MFMA, swapped operands (D cols = lane-own edge,
//         no cross-lane ops), one dwordx4 store at the edge's ROW-SORTED slot.
//   gather_out: per node, contiguous [rstart[n],rstart[n+1]) coalesced sum.
#define NN 50000
#define EE 1600000
#define BPB 96               // blocks per bucket in edge_mfma_nw
#define CH 1024              // edges per chunk
#define NCHUNK ((EE + CH - 1) / CH)   // 1563

typedef __attribute__((ext_vector_type(8))) short  s16x8;   // 8 bf16 (4 VGPRs)
typedef __attribute__((ext_vector_type(4))) float  f32x4;   // MFMA C/D frag

static __device__ __forceinline__ short f2bs(float x) {
  __hip_bfloat16 h = __float2bfloat16(x);
  short s; __builtin_memcpy(&s, &h, 2); return s;
}

__constant__ int kOffs[8] = {0, 1, 4, 5, 16, 17, 20, 21};

// ---------------------------------------------------------------------------
// prep (fused): blocks [0,32) conv_w ; [32,160) pack_f ; [160,160+NCHUNK)
// per-chunk histogram + row-rank.
// conv_w: W fp32 [k][i][o] -> bf16 frag layout (tile t=kmat*2+oh; frag elem
// (t,l,j) = W[kmat][(l>>4)*8+j][oh*16+(l&15)]).  Read as an MFMA A-frag this
// is W^T (A[o][k]); read as a B-frag it is W (B[k][o]) — same bytes.
// pack_f: f fp32 [N][32] -> bf16 [N][32] (3.2 MB; the per-edge MFMA operand).
// hist chunk c: bucket q = b0+3*b1+9*b2 of each of the chunk's 1024 edges,
// LDS 27-bin count -> bh[q*NCHUNK+c]; rrank[e] = atomicAdd(&degi[row],1).
// ---------------------------------------------------------------------------
#define PREP_BLOCKS (160 + NCHUNK)
__global__ __launch_bounds__(256) void prep(const float* __restrict__ W,
                                            const float* __restrict__ f,
                                            const float* __restrict__ pseudo,
                                            const int* __restrict__ ei,
                                            short* __restrict__ Wb,
                                            short* __restrict__ fbh,
                                            int* __restrict__ bh,
                                            int* __restrict__ degi,
                                            int* __restrict__ rrank) {
  const int b = blockIdx.x;
  if (b < 32) {
    int tid = b * 256 + threadIdx.x;               // 8192 threads, one frag each
    int t = tid >> 6, l = tid & 63;
    int c = t * 16 + (l & 15);
    int k0 = (l >> 4) * 8;
    s16x8 frag;
#pragma unroll
    for (int j = 0; j < 8; ++j)
      frag[j] = f2bs(W[(c >> 5) * 1024 + (k0 + j) * 32 + (c & 31)]);
    ((s16x8*)Wb)[tid] = frag;
  } else if (b < 160) {
    for (int tid = (b - 32) * 256 + threadIdx.x; tid < NN * 32 / 8; tid += 128 * 256) {
      const f32x4* fp = (const f32x4*)f + (size_t)tid * 2;
      f32x4 a = fp[0], c = fp[1];
      s16x8 o;
#pragma unroll
      for (int j = 0; j < 4; ++j) { o[j] = f2bs(a[j]); o[4 + j] = f2bs(c[j]); }
      ((s16x8*)fbh)[tid] = o;
    }
  } else {
    __shared__ int lh[27];
    if (threadIdx.x < 27) lh[threadIdx.x] = 0;
    __syncthreads();
    const int c  = b - 160;                        // chunk id
    const int e0 = c * CH;
#pragma unroll
    for (int i = 0; i < CH / 256; ++i) {
      int e = e0 + i * 256 + threadIdx.x;
      if (e < EE) {
        float v0 = pseudo[e * 3 + 0] * 3.0f;
        float v1 = pseudo[e * 3 + 1] * 3.0f;
        float v2 = pseudo[e * 3 + 2] * 3.0f;
        int b0 = (int)fminf(fmaxf(floorf(v0), 0.0f), 2.0f);
        int b1 = (int)fminf(fmaxf(floorf(v1), 0.0f), 2.0f);
        int b2 = (int)fminf(fmaxf(floorf(v2), 0.0f), 2.0f);
        atomicAdd(&lh[b0 + 3 * b1 + 9 * b2], 1);
        rrank[e] = atomicAdd(&degi[ei[e]], 1);     // rank = atomic return
      }
    }
    __syncthreads();
    if (threadIdx.x < 27) bh[threadIdx.x * NCHUNK + c] = lh[threadIdx.x];
  }
}

// ---------------------------------------------------------------------------
// scan_combo (grid=2, 1024 threads):
//   block 0: in-place exclusive scan of bh[27*NCHUNK] (bin-major flat), then
//            bstart[q] = bh[q*NCHUNK] (bstart[27] = EE).
//   block 1: exclusive scan of degi[50000] -> rstart[0..NN].
// ---------------------------------------------------------------------------
__global__ __launch_bounds__(1024) void scan_combo(int* __restrict__ bh,
                                                   const int* __restrict__ degi,
                                                   int* __restrict__ bstart,
                                                   int* __restrict__ rstart) {
  __shared__ int carry;
  __shared__ int tot;
  __shared__ int wsum[16];
  const int lane = threadIdx.x & 63;
  const int wid  = threadIdx.x >> 6;
  if (threadIdx.x == 0) carry = 0;
  __syncthreads();
  if (blockIdx.x == 0) {
    const int L = 27 * NCHUNK;
    for (int c0 = 0; c0 < L; c0 += 1024) {
      int i = c0 + threadIdx.x;
      int v = (i < L) ? bh[i] : 0;
      int x = v;
#pragma unroll
      for (int d = 1; d < 64; d <<= 1) {
        int y = __shfl_up(x, d, 64);
        if (lane >= d) x += y;
      }
      if (lane == 63) wsum[wid] = x;
      __syncthreads();
      if (threadIdx.x == 0) {
        int run = 0;
#pragma unroll
        for (int w = 0; w < 16; ++w) { int t = wsum[w]; wsum[w] = run; run += t; }
        tot = run;
      }
      __syncthreads();
      int excl = carry + wsum[wid] + (x - v);
      if (i < L) bh[i] = excl;
      __syncthreads();
      if (threadIdx.x == 0) carry += tot;
      __syncthreads();
    }
    if (threadIdx.x < 27) bstart[threadIdx.x] = bh[threadIdx.x * NCHUNK];
    if (threadIdx.x == 27) bstart[27] = EE;
  } else {
    for (int c0 = 0; c0 < NN; c0 += 1024) {
      int i = c0 + threadIdx.x;
      int v = (i < NN) ? degi[i] : 0;
      int x = v;
#pragma unroll
      for (int d = 1; d < 64; d <<= 1) {
        int y = __shfl_up(x, d, 64);
        if (lane >= d) x += y;
      }
      if (lane == 63) wsum[wid] = x;
      __syncthreads();
      if (threadIdx.x == 0) {
        int run = 0;
#pragma unroll
        for (int w = 0; w < 16; ++w) { int t = wsum[w]; wsum[w] = run; run += t; }
        tot = run;
      }
      __syncthreads();
      int excl = carry + wsum[wid] + (x - v);
      if (i < NN) rstart[i] = excl;
      __syncthreads();
      if (threadIdx.x == 0) carry += tot;
      __syncthreads();
    }
    if (threadIdx.x == 0) rstart[NN] = carry;      // == EE
  }
}

// ---------------------------------------------------------------------------
// Counting-sort scatter, ZERO global atomics. 1 block = 1 chunk (same edge
// partitioning as prep's hist, so counts match exactly). Rank within
// (chunk,bin) via LDS atomics; base = pre-scanned bh[q*NCHUNK+c].
// edata[pos] = (p0,p1,p2, bitcast(col));  rpos_arr[pos] = rstart[row]+rrank[e].
// ---------------------------------------------------------------------------
__global__ __launch_bounds__(256) void bucket_scatter(const float* __restrict__ pseudo,
                                                      const int* __restrict__ ei,
                                                      const int* __restrict__ rrank,
                                                      const int* __restrict__ rstart,
                                                      const int* __restrict__ bh,
                                                      float4* __restrict__ edata,
                                                      int* __restrict__ rpos_arr) {
  __shared__ int lh[27];
  __shared__ int bb[27];
  if (threadIdx.x < 27) lh[threadIdx.x] = 0;
  __syncthreads();
  const int c  = blockIdx.x;
  const int e0 = c * CH;
  float p0[CH / 256], p1[CH / 256], p2[CH / 256];
  int rk[CH / 256], bq[CH / 256];
#pragma unroll
  for (int i = 0; i < CH / 256; ++i) {
    int e = e0 + i * 256 + threadIdx.x;
    bq[i] = -1;
    if (e < EE) {
      float a0 = pseudo[e * 3 + 0];
      float a1 = pseudo[e * 3 + 1];
      float a2 = pseudo[e * 3 + 2];
      int b0 = (int)fminf(fmaxf(floorf(a0 * 3.0f), 0.0f), 2.0f);
      int b1 = (int)fminf(fmaxf(floorf(a1 * 3.0f), 0.0f), 2.0f);
      int b2 = (int)fminf(fmaxf(floorf(a2 * 3.0f), 0.0f), 2.0f);
      int q = b0 + 3 * b1 + 9 * b2;
      p0[i] = a0; p1[i] = a1; p2[i] = a2;
      rk[i] = atomicAdd(&lh[q], 1);
      bq[i] = q;
    }
  }
  __syncthreads();
  if (threadIdx.x < 27) bb[threadIdx.x] = bh[threadIdx.x * NCHUNK + c];
  __syncthreads();
#pragma unroll
  for (int i = 0; i < CH / 256; ++i) {
    if (bq[i] < 0) continue;
    int e = e0 + i * 256 + threadIdx.x;
    int pos = bb[bq[i]] + rk[i];
    int row = ei[e], col = ei[EE + e];
    edata[pos] = make_float4(p0[i], p1[i], p2[i], __int_as_float(col));
    rpos_arr[pos] = rstart[row] + rrank[e];        // non-atomic L2-hit read
  }
}

// ---------------------------------------------------------------------------
// Bucketed MFMA, atomic-free, SWAPPED OPERANDS. Per group of 16 edges:
//   D = mfma(A=W^T tile (Wb frag), B=f^T (fbh frag), 0)
//   -> D[row=(l>>4)*4+r = o-channel][col=l&15 = edge]  (m89 layout).
// Lane l owns edge m=l&15: it loads edata/rpos for m, supplies the B k-chunk
// kq=l>>4 of m's features, and receives D channels o=kq*4+r of edge m.
//   acc += w_s(own edge) * d_s   -- fp32, exact weights, NO cross-lane ops.
// Store: ONE dwordx4 per lane: msg4[rp*4+kq] = {pk(o,o+16)}_{r=0..3}
// (channel-pair convention matches gather_out: word o' = (ch o', ch o'+16)).
// Next-group edata/rpos/B-frag prefetched to hide gather latency.
// ---------------------------------------------------------------------------
__global__ __launch_bounds__(256) void edge_mfma_nw(const float4* __restrict__ edata,
                                                    const int* __restrict__ rpos_arr,
                                                    const short* __restrict__ fbh,
                                                    const short* __restrict__ Wb,
                                                    const int* __restrict__ bstart,
                                                    uint4* __restrict__ msg4) {
  const int q   = blockIdx.x / BPB;
  const int sub = blockIdx.x % BPB;
  const int l   = threadIdx.x & 63;
  const int wid = threadIdx.x >> 6;

  const int start = bstart[q];
  const int end   = bstart[q + 1];
  const int nE    = end - start;
  if (nE <= 0) return;
  const int ngroups = (nE + 15) >> 4;

  const int b0 = q % 3, b1 = (q / 3) % 3, b2 = q / 9;
  const int base = b0 + 4 * b1 + 16 * b2;
  const int ko[8] = {0, 1, 4, 5, 16, 17, 20, 21};

  s16x8 bf[8][2];                                  // bucket's W frags, 64 VGPRs
#pragma unroll
  for (int s = 0; s < 8; ++s) {
    int kmat = base + ko[s];
#pragma unroll
    for (int oh = 0; oh < 2; ++oh)
      bf[s][oh] = ((const s16x8*)Wb)[(kmat * 2 + oh) * 64 + l];
  }

  const int m   = l & 15;         // edge-in-group OWNED by this lane
  const int kq  = l >> 4;         // B k-chunk / D o-quarter
  const int stride = BPB * 4;

  int g = sub * 4 + wid;
  if (g >= ngroups) return;

  int idx = start + g * 16 + m;
  int cidx = idx < end ? idx : start;
  float4 ed = edata[cidx];
  int    rp = rpos_arr[cidx];
  s16x8  af = ((const s16x8*)fbh)[(size_t)__float_as_int(ed.w) * 4 + kq];

  while (true) {
    const int gn = g + stride;
    const bool more = gn < ngroups;
    int idxn = start + gn * 16 + m;
    int cidxn = (more && idxn < end) ? idxn : start;
    float4 edn = edata[cidxn];                     // prefetch
    int    rpn = rpos_arr[cidxn];

    // spline weights of this lane's OWN edge (tail lanes: garbage is fine,
    // their store is skipped; garbage B columns stay in garbage D columns)
    float f0 = ed.x * 3.0f - (float)b0;
    float f1 = ed.y * 3.0f - (float)b1;
    float f2 = ed.z * 3.0f - (float)b2;
    float g0 = 1.0f - f0, g1c = 1.0f - f1, g2c = 1.0f - f2;
    float w8[8];
    w8[0] = g0 * g1c * g2c; w8[1] = f0 * g1c * g2c;
    w8[2] = g0 * f1 * g2c;  w8[3] = f0 * f1 * g2c;
    w8[4] = g0 * g1c * f2;  w8[5] = f0 * g1c * f2;
    w8[6] = g0 * f1 * f2;   w8[7] = f0 * f1 * f2;

    // prefetch next B-frag (hides fbh gather under MFMA+store)
    s16x8 afn = ((const s16x8*)fbh)[(size_t)__float_as_int(edn.w) * 4 + kq];

    f32x4 acc0 = {0.f, 0.f, 0.f, 0.f}, acc1 = {0.f, 0.f, 0.f, 0.f};
#pragma unroll
    for (int s = 0; s < 8; ++s) {
      f32x4 d0 = __builtin_amdgcn_mfma_f32_16x16x32_bf16(bf[s][0], af,
                   (f32x4){0.f, 0.f, 0.f, 0.f}, 0, 0, 0);   // o = 0..15
      f32x4 d1 = __builtin_amdgcn_mfma_f32_16x16x32_bf16(bf[s][1], af,
                   (f32x4){0.f, 0.f, 0.f, 0.f}, 0, 0, 0);   // o = 16..31
      float ws = w8[s];
#pragma unroll
      for (int r = 0; r < 4; ++r) {
        acc0[r] += ws * d0[r];
        acc1[r] += ws * d1[r];
      }
    }

    if (g * 16 + m < nE) {                         // lane's own edge valid?
      uint4 pk;
      pk.x = (unsigned)(unsigned short)f2bs(acc0[0]) |
             ((unsigned)(unsigned short)f2bs(acc1[0]) << 16);
      pk.y = (unsigned)(unsigned short)f2bs(acc0[1]) |
             ((unsigned)(unsigned short)f2bs(acc1[1]) << 16);
      pk.z = (unsigned)(unsigned short)f2bs(acc0[2]) |
             ((unsigned)(unsigned short)f2bs(acc1[2]) << 16);
      pk.w = (unsigned)(unsigned short)f2bs(acc0[3]) |
             ((unsigned)(unsigned short)f2bs(acc1[3]) << 16);
      msg4[(size_t)rp * 4 + kq] = pk;              // one 16 B store per lane
    }

    if (!more) break;
    g = gn; ed = edn; af = afn; rp = rpn;
  }
}

// ---------------------------------------------------------------------------
// Per-node gather: 16 lanes/node. Messages for node n are CONTIGUOUS slots
// [rstart[n], rstart[n+1]) -> fully coalesced stream. Sum bf16 in fp32,
// divide by deg, add bias. Single writer, no atomics, no indirection.
// Lane j holds channels o=j (lo halves) and o=j+16 (hi halves).
// ---------------------------------------------------------------------------
__global__ __launch_bounds__(256) void gather_out(const unsigned* __restrict__ msg,
                                                  const int* __restrict__ rstart,
                                                  const float* __restrict__ bias,
                                                  float* __restrict__ out) {
  int n = (blockIdx.x * 256 + threadIdx.x) >> 4;   // node
  int j = threadIdx.x & 15;
  if (n >= NN) return;
  int s = rstart[n], e = rstart[n + 1];
  int cnt = e - s;
  const unsigned* mp = msg + (size_t)s * 16 + j;
  float s0 = 0.f, s1 = 0.f;
  int i = 0;
  for (; i + 4 <= cnt; i += 4) {                   // unroll-4 for MLP
    unsigned uA = mp[(size_t)(i + 0) * 16];
    unsigned uB = mp[(size_t)(i + 1) * 16];
    unsigned uC = mp[(size_t)(i + 2) * 16];
    unsigned uD = mp[(size_t)(i + 3) * 16];
    s0 += __uint_as_float(uA << 16); s1 += __uint_as_float(uA & 0xFFFF0000u);
    s0 += __uint_as_float(uB << 16); s1 += __uint_as_float(uB & 0xFFFF0000u);
    s0 += __uint_as_float(uC << 16); s1 += __uint_as_float(uC & 0xFFFF0000u);
    s0 += __uint_as_float(uD << 16); s1 += __uint_as_float(uD & 0xFFFF0000u);
  }
  for (; i < cnt; ++i) {
    unsigned u = mp[(size_t)i * 16];
    s0 += __uint_as_float(u << 16);
    s1 += __uint_as_float(u & 0xFFFF0000u);
  }
  float d = fmaxf((float)cnt, 1.0f);
  out[n * 32 + j]      = s0 / d + bias[j];
  out[n * 32 + 16 + j] = s1 / d + bias[16 + j];
}

// ---------------------------------------------------------------------------
// Fallback path (small workspace): direct per-edge compute + atomics.
// ---------------------------------------------------------------------------
static __device__ __forceinline__ void spline_basis(const float* __restrict__ pseudo,
                                                    int e, float w[8], int& base) {
  float v0 = pseudo[e * 3 + 0] * 3.0f;
  float v1 = pseudo[e * 3 + 1] * 3.0f;
  float v2 = pseudo[e * 3 + 2] * 3.0f;
  float b0 = fmaxf(fminf(floorf(v0), 2.0f), 0.0f);
  float b1 = fmaxf(fminf(floorf(v1), 2.0f), 0.0f);
  float b2 = fmaxf(fminf(floorf(v2), 2.0f), 0.0f);
  float f0 = v0 - b0, f1 = v1 - b1, f2 = v2 - b2;
  float g0 = 1.0f - f0, g1 = 1.0f - f1, g2 = 1.0f - f2;
  base = (int)b0 + 4 * (int)b1 + 16 * (int)b2;
  w[0] = g0 * g1 * g2; w[1] = f0 * g1 * g2;
  w[2] = g0 * f1 * g2; w[3] = f0 * f1 * g2;
  w[4] = g0 * g1 * f2; w[5] = f0 * g1 * f2;
  w[6] = g0 * f1 * f2; w[7] = f0 * f1 * f2;
}

__global__ __launch_bounds__(256) void edge_direct(const float* __restrict__ pseudo,
                                                   const int* __restrict__ ei,
                                                   const float* __restrict__ f,
                                                   const float* __restrict__ W,
                                                   float* __restrict__ acc,
                                                   float* __restrict__ deg) {
  const int tid = blockIdx.x * 256 + threadIdx.x;
  const int e = tid >> 5;
  const int o = tid & 31;
  if (e >= EE) return;
  const int row = ei[e];
  const int col = ei[EE + e];
  float w[8]; int base;
  spline_basis(pseudo, e, w, base);
  const float myf = f[col * 32 + o];
  float a = 0.0f;
  for (int i = 0; i < 32; ++i) {
    float fi = __shfl(myf, i, 32);
    float wsum = 0.0f;
#pragma unroll
    for (int s = 0; s < 8; ++s)
      wsum += w[s] * W[(size_t)(base + kOffs[s]) * 1024 + i * 32 + o];
    a += fi * wsum;
  }
  atomicAdd(acc + (size_t)row * 32 + o, a);
  if (o == 0) atomicAdd(deg + row, 1.0f);
}

__global__ __launch_bounds__(256) void finalize(const float* __restrict__ acc,
                                                const float* __restrict__ deg,
                                                const float* __restrict__ bias,
                                                float* __restrict__ out) {
  int tid = blockIdx.x * 256 + threadIdx.x;
  if (tid >= NN * 32) return;
  int n = tid >> 5, o = tid & 31;
  float d = fmaxf(deg[n], 1.0f);
  out[tid] = acc[tid] / d + bias[o];
}

extern "C" void kernel_launch(void* const* d_in, const int* in_sizes, int n_in,
                              void* d_out, int out_size, void* d_ws, size_t ws_size,
                              hipStream_t stream) {
  const float* f      = (const float*)d_in[0];
  const float* pseudo = (const float*)d_in[1];
  const float* W      = (const float*)d_in[2];
  const float* bias   = (const float*)d_in[3];
  const int*   ei     = (const int*)d_in[4];
  float* out = (float*)d_out;

  // Workspace layout (~144.7 MB total; big path verified in rounds 4-6)
  constexpr size_t DEGI_OFF  = 0;                              // NN ints
  constexpr size_t ZERO_SZ   = 200064;                         // memset: degi
  constexpr size_t BST_OFF   = 200064;                         // 28 ints
  constexpr size_t RST_OFF   = 200320;                         // NN+1 ints
  constexpr size_t BH_OFF    = 400384;                         // 27*NCHUNK ints
  constexpr size_t RRANK_OFF = 569344;                         // EE ints
  constexpr size_t ED_OFF    = RRANK_OFF + (size_t)EE * 4;     //   6,969,344
  constexpr size_t RPOS_OFF  = ED_OFF + (size_t)EE * 16;       //  32,569,344
  constexpr size_t MSG_OFF   = RPOS_OFF + (size_t)EE * 4;      //  38,969,344
  constexpr size_t FBH_OFF   = MSG_OFF + (size_t)EE * 64;      // 141,369,344
  constexpr size_t WB_OFF    = FBH_OFF + (size_t)NN * 64;      // 144,569,344
  constexpr size_t TOTAL     = WB_OFF + 128 * 64 * 8 * 2;      // 144,700,416

  char* ws = (char*)d_ws;

  if (ws_size >= TOTAL) {
    int*      degi  = (int*)(ws + DEGI_OFF);
    int*      bst   = (int*)(ws + BST_OFF);
    int*      rst   = (int*)(ws + RST_OFF);
    int*      bh    = (int*)(ws + BH_OFF);
    int*      rrank = (int*)(ws + RRANK_OFF);
    float4*   edata = (float4*)(ws + ED_OFF);
    int*      rpos  = (int*)(ws + RPOS_OFF);
    uint4*    msg4  = (uint4*)(ws + MSG_OFF);
    unsigned* msg   = (unsigned*)(ws + MSG_OFF);
    short*    fbh   = (short*)(ws + FBH_OFF);
    short*    Wb    = (short*)(ws + WB_OFF);

    hipMemsetAsync(ws, 0, ZERO_SZ, stream);
    prep<<<PREP_BLOCKS, 256, 0, stream>>>(W, f, pseudo, ei, Wb, fbh, bh, degi, rrank);
    scan_combo<<<2, 1024, 0, stream>>>(bh, degi, bst, rst);
    bucket_scatter<<<NCHUNK, 256, 0, stream>>>(pseudo, ei, rrank, rst, bh, edata, rpos);
    edge_mfma_nw<<<27 * BPB, 256, 0, stream>>>(edata, rpos, fbh, Wb, bst, msg4);
    gather_out<<<(NN * 16 + 255) / 256, 256, 0, stream>>>(msg, rst, bias, out);
  } else {
    constexpr size_t ACC_SZ = (size_t)NN * 32 * 4;
    float* acc = (float*)ws;
    float* deg = (float*)(ws + ACC_SZ);
    hipMemsetAsync(acc, 0, ACC_SZ + (size_t)NN * 4, stream);
    edge_direct<<<(EE * 32) / 256, 256, 0, stream>>>(pseudo, ei, f, W, acc, deg);
    finalize<<<(NN * 32) / 256, 256, 0, stream>>>(acc, deg, bias, out);
  }
}

// Round 8
// 294.219 us; speedup vs baseline: 1.6068x; 1.0174x over previous
//
#include <hip/hip_runtime.h>
#include <hip/hip_bf16.h>

// Problem constants: N=50000, E=1600000, D=3, IN=32, OUT=32, KS=4, K=64, S=8
// Fully deterministic sort structure — ZERO scattered global atomics:
//   group_rank: G=128 edge-groups; per-group FULL 50K-row histogram in LDS
//       (packed 2 rows/u32, 100 KB); LDS atomic return = lrank[e] (u16);
//       dump per-group counts gcnt[g][row].
//   prep: pack W/f to bf16 + per-chunk 27-bin bucket histogram (streaming).
//   deg_total: degi[row] = sum_g gcnt[g][row].
//   scan_combo: blk0 scans bh[27][NCHUNK] (bucket starts); blk1 scans degi
//       -> rstart (row-CSR).
//   group_base: in-place gcnt[g][row] = rstart[row] + prefix_g (batched).
//   bucket_scatter: 1 block = 1 chunk; base from pre-scanned bh; LDS rank
//       atomics only. rpos = gcnt[e/GSZ][row] + lrank[e].
//   edge_mfma_nw: per-bucket MFMA, swapped operands, one dwordx4 store at
//       the edge's row-sorted slot (full 64 B line per edge).
//   gather_out: per node, contiguous [rstart[n],rstart[n+1]) coalesced sum.
#define NN 50000
#define EE 1600000
#define BPB 96               // blocks per bucket in edge_mfma_nw
#define CH 1024              // edges per chunk (bucket hist/scatter)
#define NCHUNK ((EE + CH - 1) / CH)   // 1563
#define GG 128               // rank groups
#define GSZ (EE / GG)        // 12500 edges per group (exact)

typedef __attribute__((ext_vector_type(8))) short  s16x8;   // 8 bf16 (4 VGPRs)
typedef __attribute__((ext_vector_type(4))) float  f32x4;   // MFMA C/D frag

static __device__ __forceinline__ short f2bs(float x) {
  __hip_bfloat16 h = __float2bfloat16(x);
  short s; __builtin_memcpy(&s, &h, 2); return s;
}

__constant__ int kOffs[8] = {0, 1, 4, 5, 16, 17, 20, 21};

// ---------------------------------------------------------------------------
// group_rank: block g owns edges [g*GSZ, (g+1)*GSZ). Full-row histogram in
// LDS (2 rows packed per u32; per-half count <= GSZ=12500 < 65536 so the
// halves never carry into each other). LDS atomic RETURN is the within-
// (group,row) rank -> lrank[e]. Counts dumped to gcnt[g][row].
// ---------------------------------------------------------------------------
__global__ __launch_bounds__(256) void group_rank(const int* __restrict__ ei,
                                                  unsigned short* __restrict__ lrank,
                                                  int* __restrict__ gcnt) {
  __shared__ unsigned lh32[NN / 2];                // 25000 words = 100 KB
  for (int j = threadIdx.x; j < NN / 2; j += 256) lh32[j] = 0;
  __syncthreads();
  const int g  = blockIdx.x;
  const int e0 = g * GSZ;
  for (int i = threadIdx.x; i < GSZ; i += 256) {
    int e = e0 + i;
    int row = ei[e];
    unsigned add = (row & 1) ? 0x10000u : 1u;
    unsigned ret = atomicAdd(&lh32[row >> 1], add);
    unsigned r = (row & 1) ? (ret >> 16) : (ret & 0xFFFFu);
    lrank[e] = (unsigned short)r;
  }
  __syncthreads();
  for (int j = threadIdx.x; j < NN / 2; j += 256) {
    unsigned u = lh32[j];
    gcnt[(size_t)g * NN + 2 * j]     = (int)(u & 0xFFFFu);
    gcnt[(size_t)g * NN + 2 * j + 1] = (int)(u >> 16);
  }
}

// ---------------------------------------------------------------------------
// prep (fused): blocks [0,32) conv_w ; [32,160) pack_f ; [160,160+NCHUNK)
// per-chunk 27-bin bucket histogram (streaming, LDS-only atomics).
// conv_w: W fp32 [k][i][o] -> bf16 frag layout (tile t=kmat*2+oh; frag elem
// (t,l,j) = W[kmat][(l>>4)*8+j][oh*16+(l&15)]).
// pack_f: f fp32 [N][32] -> bf16 [N][32] (3.2 MB; the per-edge MFMA operand).
// ---------------------------------------------------------------------------
#define PREP_BLOCKS (160 + NCHUNK)
__global__ __launch_bounds__(256) void prep(const float* __restrict__ W,
                                            const float* __restrict__ f,
                                            const float* __restrict__ pseudo,
                                            short* __restrict__ Wb,
                                            short* __restrict__ fbh,
                                            int* __restrict__ bh) {
  const int b = blockIdx.x;
  if (b < 32) {
    int tid = b * 256 + threadIdx.x;               // 8192 threads, one frag each
    int t = tid >> 6, l = tid & 63;
    int c = t * 16 + (l & 15);
    int k0 = (l >> 4) * 8;
    s16x8 frag;
#pragma unroll
    for (int j = 0; j < 8; ++j)
      frag[j] = f2bs(W[(c >> 5) * 1024 + (k0 + j) * 32 + (c & 31)]);
    ((s16x8*)Wb)[tid] = frag;
  } else if (b < 160) {
    for (int tid = (b - 32) * 256 + threadIdx.x; tid < NN * 32 / 8; tid += 128 * 256) {
      const f32x4* fp = (const f32x4*)f + (size_t)tid * 2;
      f32x4 a = fp[0], c = fp[1];
      s16x8 o;
#pragma unroll
      for (int j = 0; j < 4; ++j) { o[j] = f2bs(a[j]); o[4 + j] = f2bs(c[j]); }
      ((s16x8*)fbh)[tid] = o;
    }
  } else {
    __shared__ int lh[27];
    if (threadIdx.x < 27) lh[threadIdx.x] = 0;
    __syncthreads();
    const int c  = b - 160;                        // chunk id
    const int e0 = c * CH;
#pragma unroll
    for (int i = 0; i < CH / 256; ++i) {
      int e = e0 + i * 256 + threadIdx.x;
      if (e < EE) {
        float v0 = pseudo[e * 3 + 0] * 3.0f;
        float v1 = pseudo[e * 3 + 1] * 3.0f;
        float v2 = pseudo[e * 3 + 2] * 3.0f;
        int b0 = (int)fminf(fmaxf(floorf(v0), 0.0f), 2.0f);
        int b1 = (int)fminf(fmaxf(floorf(v1), 0.0f), 2.0f);
        int b2 = (int)fminf(fmaxf(floorf(v2), 0.0f), 2.0f);
        atomicAdd(&lh[b0 + 3 * b1 + 9 * b2], 1);
      }
    }
    __syncthreads();
    if (threadIdx.x < 27) bh[threadIdx.x * NCHUNK + c] = lh[threadIdx.x];
  }
}

// ---------------------------------------------------------------------------
// deg_total: degi[row] = sum over groups of gcnt[g][row] (coalesced per g).
// ---------------------------------------------------------------------------
__global__ __launch_bounds__(256) void deg_total(const int* __restrict__ gcnt,
                                                 int* __restrict__ degi) {
  int row = blockIdx.x * 256 + threadIdx.x;
  if (row >= NN) return;
  int s = 0;
#pragma unroll 8
  for (int g = 0; g < GG; ++g) s += gcnt[(size_t)g * NN + row];
  degi[row] = s;
}

// ---------------------------------------------------------------------------
// scan_combo (grid=2, 1024 threads):
//   block 0: in-place exclusive scan of bh[27*NCHUNK] (bin-major flat), then
//            bstart[q] = bh[q*NCHUNK] (bstart[27] = EE).
//   block 1: exclusive scan of degi[50000] -> rstart[0..NN].
// ---------------------------------------------------------------------------
__global__ __launch_bounds__(1024) void scan_combo(int* __restrict__ bh,
                                                   const int* __restrict__ degi,
                                                   int* __restrict__ bstart,
                                                   int* __restrict__ rstart) {
  __shared__ int carry;
  __shared__ int tot;
  __shared__ int wsum[16];
  const int lane = threadIdx.x & 63;
  const int wid  = threadIdx.x >> 6;
  if (threadIdx.x == 0) carry = 0;
  __syncthreads();
  if (blockIdx.x == 0) {
    const int L = 27 * NCHUNK;
    for (int c0 = 0; c0 < L; c0 += 1024) {
      int i = c0 + threadIdx.x;
      int v = (i < L) ? bh[i] : 0;
      int x = v;
#pragma unroll
      for (int d = 1; d < 64; d <<= 1) {
        int y = __shfl_up(x, d, 64);
        if (lane >= d) x += y;
      }
      if (lane == 63) wsum[wid] = x;
      __syncthreads();
      if (threadIdx.x == 0) {
        int run = 0;
#pragma unroll
        for (int w = 0; w < 16; ++w) { int t = wsum[w]; wsum[w] = run; run += t; }
        tot = run;
      }
      __syncthreads();
      int excl = carry + wsum[wid] + (x - v);
      if (i < L) bh[i] = excl;
      __syncthreads();
      if (threadIdx.x == 0) carry += tot;
      __syncthreads();
    }
    if (threadIdx.x < 27) bstart[threadIdx.x] = bh[threadIdx.x * NCHUNK];
    if (threadIdx.x == 27) bstart[27] = EE;
  } else {
    for (int c0 = 0; c0 < NN; c0 += 1024) {
      int i = c0 + threadIdx.x;
      int v = (i < NN) ? degi[i] : 0;
      int x = v;
#pragma unroll
      for (int d = 1; d < 64; d <<= 1) {
        int y = __shfl_up(x, d, 64);
        if (lane >= d) x += y;
      }
      if (lane == 63) wsum[wid] = x;
      __syncthreads();
      if (threadIdx.x == 0) {
        int run = 0;
#pragma unroll
        for (int w = 0; w < 16; ++w) { int t = wsum[w]; wsum[w] = run; run += t; }
        tot = run;
      }
      __syncthreads();
      int excl = carry + wsum[wid] + (x - v);
      if (i < NN) rstart[i] = excl;
      __syncthreads();
      if (threadIdx.x == 0) carry += tot;
      __syncthreads();
    }
    if (threadIdx.x == 0) rstart[NN] = carry;      // == EE
  }
}

// ---------------------------------------------------------------------------
// group_base: in-place gcnt[g][row] = rstart[row] + prefix over g'<g.
// Loads batched 8-wide so the 128-step chain isn't latency-serialized.
// ---------------------------------------------------------------------------
__global__ __launch_bounds__(256) void group_base(int* __restrict__ gcnt,
                                                  const int* __restrict__ rstart) {
  int row = blockIdx.x * 256 + threadIdx.x;
  if (row >= NN) return;
  int run = rstart[row];
  for (int g0 = 0; g0 < GG; g0 += 8) {
    int t[8];
#pragma unroll
    for (int j = 0; j < 8; ++j) t[j] = gcnt[(size_t)(g0 + j) * NN + row];
#pragma unroll
    for (int j = 0; j < 8; ++j) {
      int v = t[j];
      gcnt[(size_t)(g0 + j) * NN + row] = run;
      run += v;
    }
  }
}

// ---------------------------------------------------------------------------
// Counting-sort scatter, ZERO global atomics. 1 block = 1 chunk (same edge
// partitioning as prep's hist). Rank within (chunk,bin) via LDS atomics;
// base = pre-scanned bh[q*NCHUNK+c].
// edata[pos] = (p0,p1,p2, bitcast(col));
// rpos_arr[pos] = gcnt[e/GSZ][row] + lrank[e]   (row-sorted message slot).
// ---------------------------------------------------------------------------
__global__ __launch_bounds__(256) void bucket_scatter(const float* __restrict__ pseudo,
                                                      const int* __restrict__ ei,
                                                      const unsigned short* __restrict__ lrank,
                                                      const int* __restrict__ gcnt,
                                                      const int* __restrict__ bh,
                                                      float4* __restrict__ edata,
                                                      int* __restrict__ rpos_arr) {
  __shared__ int lh[27];
  __shared__ int bb[27];
  if (threadIdx.x < 27) lh[threadIdx.x] = 0;
  __syncthreads();
  if (threadIdx.x < 27) bb[threadIdx.x] = bh[threadIdx.x * NCHUNK + blockIdx.x];
  const int e0 = blockIdx.x * CH;
#pragma unroll
  for (int i = 0; i < CH / 256; ++i) {
    int e = e0 + i * 256 + threadIdx.x;
    if (e < EE) {
      float a0 = pseudo[e * 3 + 0];
      float a1 = pseudo[e * 3 + 1];
      float a2 = pseudo[e * 3 + 2];
      int b0 = (int)fminf(fmaxf(floorf(a0 * 3.0f), 0.0f), 2.0f);
      int b1 = (int)fminf(fmaxf(floorf(a1 * 3.0f), 0.0f), 2.0f);
      int b2 = (int)fminf(fmaxf(floorf(a2 * 3.0f), 0.0f), 2.0f);
      int q = b0 + 3 * b1 + 9 * b2;
      int rk = atomicAdd(&lh[q], 1);
      int pos = bb[q] + rk;                        // bb valid: written pre-loop,
      int row = ei[e], col = ei[EE + e];           // same-wave visibility + the
      int ge  = e / GSZ;                           // syncthreads above for others
      edata[pos] = make_float4(a0, a1, a2, __int_as_float(col));
      rpos_arr[pos] = gcnt[(size_t)ge * NN + row] + (int)lrank[e];
    }
  }
}

// ---------------------------------------------------------------------------
// Bucketed MFMA, atomic-free, SWAPPED OPERANDS. Per group of 16 edges:
//   D = mfma(A=W^T tile (Wb frag), B=f^T (fbh frag), 0)
//   -> D[row=(l>>4)*4+r = o-channel][col=l&15 = edge]  (m89 layout).
// Lane l owns edge m=l&15; weights + rpos are lane-local (no cross-lane ops).
// Store: ONE dwordx4 per lane: msg4[rp*4+kq] = {pk(o,o+16)}_{r=0..3}.
// ---------------------------------------------------------------------------
__global__ __launch_bounds__(256) void edge_mfma_nw(const float4* __restrict__ edata,
                                                    const int* __restrict__ rpos_arr,
                                                    const short* __restrict__ fbh,
                                                    const short* __restrict__ Wb,
                                                    const int* __restrict__ bstart,
                                                    uint4* __restrict__ msg4) {
  const int q   = blockIdx.x / BPB;
  const int sub = blockIdx.x % BPB;
  const int l   = threadIdx.x & 63;
  const int wid = threadIdx.x >> 6;

  const int start = bstart[q];
  const int end   = bstart[q + 1];
  const int nE    = end - start;
  if (nE <= 0) return;
  const int ngroups = (nE + 15) >> 4;

  const int b0 = q % 3, b1 = (q / 3) % 3, b2 = q / 9;
  const int base = b0 + 4 * b1 + 16 * b2;
  const int ko[8] = {0, 1, 4, 5, 16, 17, 20, 21};

  s16x8 bf[8][2];                                  // bucket's W frags, 64 VGPRs
#pragma unroll
  for (int s = 0; s < 8; ++s) {
    int kmat = base + ko[s];
#pragma unroll
    for (int oh = 0; oh < 2; ++oh)
      bf[s][oh] = ((const s16x8*)Wb)[(kmat * 2 + oh) * 64 + l];
  }

  const int m   = l & 15;         // edge-in-group OWNED by this lane
  const int kq  = l >> 4;         // B k-chunk / D o-quarter
  const int stride = BPB * 4;

  int g = sub * 4 + wid;
  if (g >= ngroups) return;

  int idx = start + g * 16 + m;
  int cidx = idx < end ? idx : start;
  float4 ed = edata[cidx];
  int    rp = rpos_arr[cidx];
  s16x8  af = ((const s16x8*)fbh)[(size_t)__float_as_int(ed.w) * 4 + kq];

  while (true) {
    const int gn = g + stride;
    const bool more = gn < ngroups;
    int idxn = start + gn * 16 + m;
    int cidxn = (more && idxn < end) ? idxn : start;
    float4 edn = edata[cidxn];                     // prefetch
    int    rpn = rpos_arr[cidxn];

    // spline weights of this lane's OWN edge (tail lanes: garbage is fine,
    // their store is skipped; garbage B columns stay in garbage D columns)
    float f0 = ed.x * 3.0f - (float)b0;
    float f1 = ed.y * 3.0f - (float)b1;
    float f2 = ed.z * 3.0f - (float)b2;
    float g0 = 1.0f - f0, g1c = 1.0f - f1, g2c = 1.0f - f2;
    float w8[8];
    w8[0] = g0 * g1c * g2c; w8[1] = f0 * g1c * g2c;
    w8[2] = g0 * f1 * g2c;  w8[3] = f0 * f1 * g2c;
    w8[4] = g0 * g1c * f2;  w8[5] = f0 * g1c * f2;
    w8[6] = g0 * f1 * f2;   w8[7] = f0 * f1 * f2;

    // prefetch next B-frag (hides fbh gather under MFMA+store)
    s16x8 afn = ((const s16x8*)fbh)[(size_t)__float_as_int(edn.w) * 4 + kq];

    f32x4 acc0 = {0.f, 0.f, 0.f, 0.f}, acc1 = {0.f, 0.f, 0.f, 0.f};
#pragma unroll
    for (int s = 0; s < 8; ++s) {
      f32x4 d0 = __builtin_amdgcn_mfma_f32_16x16x32_bf16(bf[s][0], af,
                   (f32x4){0.f, 0.f, 0.f, 0.f}, 0, 0, 0);   // o = 0..15
      f32x4 d1 = __builtin_amdgcn_mfma_f32_16x16x32_bf16(bf[s][1], af,
                   (f32x4){0.f, 0.f, 0.f, 0.f}, 0, 0, 0);   // o = 16..31
      float ws = w8[s];
#pragma unroll
      for (int r = 0; r < 4; ++r) {
        acc0[r] += ws * d0[r];
        acc1[r] += ws * d1[r];
      }
    }

    if (g * 16 + m < nE) {                         // lane's own edge valid?
      uint4 pk;
      pk.x = (unsigned)(unsigned short)f2bs(acc0[0]) |
             ((unsigned)(unsigned short)f2bs(acc1[0]) << 16);
      pk.y = (unsigned)(unsigned short)f2bs(acc0[1]) |
             ((unsigned)(unsigned short)f2bs(acc1[1]) << 16);
      pk.z = (unsigned)(unsigned short)f2bs(acc0[2]) |
             ((unsigned)(unsigned short)f2bs(acc1[2]) << 16);
      pk.w = (unsigned)(unsigned short)f2bs(acc0[3]) |
             ((unsigned)(unsigned short)f2bs(acc1[3]) << 16);
      msg4[(size_t)rp * 4 + kq] = pk;              // one 16 B store per lane
    }

    if (!more) break;
    g = gn; ed = edn; af = afn; rp = rpn;
  }
}

// ---------------------------------------------------------------------------
// Per-node gather: 16 lanes/node. Messages for node n are CONTIGUOUS slots
// [rstart[n], rstart[n+1]) -> fully coalesced stream. Sum bf16 in fp32,
// divide by deg, add bias. Single writer, no atomics, no indirection.
// Lane j holds channels o=j (lo halves) and o=j+16 (hi halves).
// ---------------------------------------------------------------------------
__global__ __launch_bounds__(256) void gather_out(const unsigned* __restrict__ msg,
                                                  const int* __restrict__ rstart,
                                                  const float* __restrict__ bias,
                                                  float* __restrict__ out) {
  int n = (blockIdx.x * 256 + threadIdx.x) >> 4;   // node
  int j = threadIdx.x & 15;
  if (n >= NN) return;
  int s = rstart[n], e = rstart[n + 1];
  int cnt = e - s;
  const unsigned* mp = msg + (size_t)s * 16 + j;
  float s0 = 0.f, s1 = 0.f;
  int i = 0;
  for (; i + 4 <= cnt; i += 4) {                   // unroll-4 for MLP
    unsigned uA = mp[(size_t)(i + 0) * 16];
    unsigned uB = mp[(size_t)(i + 1) * 16];
    unsigned uC = mp[(size_t)(i + 2) * 16];
    unsigned uD = mp[(size_t)(i + 3) * 16];
    s0 += __uint_as_float(uA << 16); s1 += __uint_as_float(uA & 0xFFFF0000u);
    s0 += __uint_as_float(uB << 16); s1 += __uint_as_float(uB & 0xFFFF0000u);
    s0 += __uint_as_float(uC << 16); s1 += __uint_as_float(uC & 0xFFFF0000u);
    s0 += __uint_as_float(uD << 16); s1 += __uint_as_float(uD & 0xFFFF0000u);
  }
  for (; i < cnt; ++i) {
    unsigned u = mp[(size_t)i * 16];
    s0 += __uint_as_float(u << 16);
    s1 += __uint_as_float(u & 0xFFFF0000u);
  }
  float d = fmaxf((float)cnt, 1.0f);
  out[n * 32 + j]      = s0 / d + bias[j];
  out[n * 32 + 16 + j] = s1 / d + bias[16 + j];
}

// ---------------------------------------------------------------------------
// Fallback path (small workspace): direct per-edge compute + atomics.
// ---------------------------------------------------------------------------
static __device__ __forceinline__ void spline_basis(const float* __restrict__ pseudo,
                                                    int e, float w[8], int& base) {
  float v0 = pseudo[e * 3 + 0] * 3.0f;
  float v1 = pseudo[e * 3 + 1] * 3.0f;
  float v2 = pseudo[e * 3 + 2] * 3.0f;
  float b0 = fmaxf(fminf(floorf(v0), 2.0f), 0.0f);
  float b1 = fmaxf(fminf(floorf(v1), 2.0f), 0.0f);
  float b2 = fmaxf(fminf(floorf(v2), 2.0f), 0.0f);
  float f0 = v0 - b0, f1 = v1 - b1, f2 = v2 - b2;
  float g0 = 1.0f - f0, g1 = 1.0f - f1, g2 = 1.0f - f2;
  base = (int)b0 + 4 * (int)b1 + 16 * (int)b2;
  w[0] = g0 * g1 * g2; w[1] = f0 * g1 * g2;
  w[2] = g0 * f1 * g2; w[3] = f0 * f1 * g2;
  w[4] = g0 * g1 * f2; w[5] = f0 * g1 * f2;
  w[6] = g0 * f1 * f2; w[7] = f0 * f1 * f2;
}

__global__ __launch_bounds__(256) void edge_direct(const float* __restrict__ pseudo,
                                                   const int* __restrict__ ei,
                                                   const float* __restrict__ f,
                                                   const float* __restrict__ W,
                                                   float* __restrict__ acc,
                                                   float* __restrict__ deg) {
  const int tid = blockIdx.x * 256 + threadIdx.x;
  const int e = tid >> 5;
  const int o = tid & 31;
  if (e >= EE) return;
  const int row = ei[e];
  const int col = ei[EE + e];
  float w[8]; int base;
  spline_basis(pseudo, e, w, base);
  const float myf = f[col * 32 + o];
  float a = 0.0f;
  for (int i = 0; i < 32; ++i) {
    float fi = __shfl(myf, i, 32);
    float wsum = 0.0f;
#pragma unroll
    for (int s = 0; s < 8; ++s)
      wsum += w[s] * W[(size_t)(base + kOffs[s]) * 1024 + i * 32 + o];
    a += fi * wsum;
  }
  atomicAdd(acc + (size_t)row * 32 + o, a);
  if (o == 0) atomicAdd(deg + row, 1.0f);
}

__global__ __launch_bounds__(256) void finalize(const float* __restrict__ acc,
                                                const float* __restrict__ deg,
                                                const float* __restrict__ bias,
                                                float* __restrict__ out) {
  int tid = blockIdx.x * 256 + threadIdx.x;
  if (tid >= NN * 32) return;
  int n = tid >> 5, o = tid & 31;
  float d = fmaxf(deg[n], 1.0f);
  out[tid] = acc[tid] / d + bias[o];
}

extern "C" void kernel_launch(void* const* d_in, const int* in_sizes, int n_in,
                              void* d_out, int out_size, void* d_ws, size_t ws_size,
                              hipStream_t stream) {
  const float* f      = (const float*)d_in[0];
  const float* pseudo = (const float*)d_in[1];
  const float* W      = (const float*)d_in[2];
  const float* bias   = (const float*)d_in[3];
  const int*   ei     = (const int*)d_in[4];
  float* out = (float*)d_out;

  // Workspace layout (~167.1 MB total; no memset needed — all fully written)
  constexpr size_t DEGI_OFF  = 0;                              // NN ints
  constexpr size_t BST_OFF   = 200064;                         // 28 ints
  constexpr size_t RST_OFF   = 200192;                         // NN+1 ints
  constexpr size_t BH_OFF    = 400256;                         // 27*NCHUNK ints
  constexpr size_t LRANK_OFF = 569088;                         // EE u16
  constexpr size_t GCNT_OFF  = LRANK_OFF + (size_t)EE * 2;     //   3,769,088
  constexpr size_t ED_OFF    = GCNT_OFF + (size_t)GG * NN * 4; //  29,369,088
  constexpr size_t RPOS_OFF  = ED_OFF + (size_t)EE * 16;       //  54,969,088
  constexpr size_t MSG_OFF   = RPOS_OFF + (size_t)EE * 4;      //  61,369,088
  constexpr size_t FBH_OFF   = MSG_OFF + (size_t)EE * 64;      // 163,769,088
  constexpr size_t WB_OFF    = FBH_OFF + (size_t)NN * 64;      // 166,969,088
  constexpr size_t TOTAL     = WB_OFF + 128 * 64 * 8 * 2;      // 167,100,160

  char* ws = (char*)d_ws;

  if (ws_size >= TOTAL) {
    int*            degi  = (int*)(ws + DEGI_OFF);
    int*            bst   = (int*)(ws + BST_OFF);
    int*            rst   = (int*)(ws + RST_OFF);
    int*            bh    = (int*)(ws + BH_OFF);
    unsigned short* lrank = (unsigned short*)(ws + LRANK_OFF);
    int*            gcnt  = (int*)(ws + GCNT_OFF);
    float4*         edata = (float4*)(ws + ED_OFF);
    int*            rpos  = (int*)(ws + RPOS_OFF);
    uint4*          msg4  = (uint4*)(ws + MSG_OFF);
    unsigned*       msg   = (unsigned*)(ws + MSG_OFF);
    short*          fbh   = (short*)(ws + FBH_OFF);
    short*          Wb    = (short*)(ws + WB_OFF);

    group_rank<<<GG, 256, 0, stream>>>(ei, lrank, gcnt);
    prep<<<PREP_BLOCKS, 256, 0, stream>>>(W, f, pseudo, Wb, fbh, bh);
    deg_total<<<(NN + 255) / 256, 256, 0, stream>>>(gcnt, degi);
    scan_combo<<<2, 1024, 0, stream>>>(bh, degi, bst, rst);
    group_base<<<(NN + 255) / 256, 256, 0, stream>>>(gcnt, rst);
    bucket_scatter<<<NCHUNK, 256, 0, stream>>>(pseudo, ei, lrank, gcnt, bh, edata, rpos);
    edge_mfma_nw<<<27 * BPB, 256, 0, stream>>>(edata, rpos, fbh, Wb, bst, msg4);
    gather_out<<<(NN * 16 + 255) / 256, 256, 0, stream>>>(msg, rst, bias, out);
  } else {
    constexpr size_t ACC_SZ = (size_t)NN * 32 * 4;
    float* acc = (float*)ws;
    float* deg = (float*)(ws + ACC_SZ);
    hipMemsetAsync(acc, 0, ACC_SZ + (size_t)NN * 4, stream);
    edge_direct<<<(EE * 32) / 256, 256, 0, stream>>>(pseudo, ei, f, W, acc, deg);
    finalize<<<(NN * 32) / 256, 256, 0, stream>>>(acc, deg, bias, out);
  }
}